// Round 3
// baseline (2401.246 us; speedup 1.0000x reference)
//
#include <hip/hip_runtime.h>
#include <math.h>

#define NBLK 256
#define NTHR 256

// ---- ws float offsets ----
#define OFF_OBS     64          // 8192
#define OFF_HS      8256        // 65536
#define OFF_EMB     73792       // 32768
#define OFF_PART    106560      // 524288  (8 kc x 512 x 128)
#define OFF_WTPOOL  630848      // 262144  (Wt_pool [2048][128])
#define OFF_WTG_E   892992      // 163840  (Wt gates enc [320][512])
#define OFF_WTG_D   1056832     // 163840  (Wt gates dec [320][512])
// total 1220672 floats ~= 4.9 MB

#define LDS_BYTES 32768

__device__ __forceinline__ void grid_barrier(unsigned* cnt, unsigned* gen) {
    __syncthreads();
    if (threadIdx.x == 0) {
        __threadfence();
        unsigned g = __hip_atomic_load(gen, __ATOMIC_RELAXED, __HIP_MEMORY_SCOPE_AGENT);
        unsigned a = __hip_atomic_fetch_add(cnt, 1u, __ATOMIC_ACQ_REL, __HIP_MEMORY_SCOPE_AGENT);
        if (a == (unsigned)(NBLK - 1)) {
            __hip_atomic_store(cnt, 0u, __ATOMIC_RELAXED, __HIP_MEMORY_SCOPE_AGENT);
            __hip_atomic_fetch_add(gen, 1u, __ATOMIC_RELEASE, __HIP_MEMORY_SCOPE_AGENT);
        } else {
            while (__hip_atomic_load(gen, __ATOMIC_ACQUIRE, __HIP_MEMORY_SCOPE_AGENT) == g)
                __builtin_amdgcn_s_sleep(2);
        }
        __threadfence();
    }
    __syncthreads();
}

__device__ __forceinline__ float sigm(float x) { return 1.f / (1.f + expf(-x)); }

__global__ void __launch_bounds__(NTHR, 1) social_lstm(
    const float* __restrict__ observed,
    const float* __restrict__ W_pos, const float* __restrict__ b_pos,
    const float* __restrict__ W_pool, const float* __restrict__ b_pool,
    const float* __restrict__ Wih_e, const float* __restrict__ bih_e,
    const float* __restrict__ Whh_e, const float* __restrict__ bhh_e,
    const float* __restrict__ Wih_d, const float* __restrict__ bih_d,
    const float* __restrict__ Whh_d, const float* __restrict__ bhh_d,
    const float* __restrict__ W_out, const float* __restrict__ b_out,
    float* __restrict__ out, float* __restrict__ ws, int npred)
{
    extern __shared__ char smem_raw[];
    const int t = threadIdx.x, b = blockIdx.x;
    const int gid = b * NTHR + t;

    unsigned* bc = (unsigned*)ws;
    unsigned* bg = bc + 1;
    float* obs     = ws + OFF_OBS;
    float* hs      = ws + OFF_HS;
    float* emb     = ws + OFF_EMB;
    float* part    = ws + OFF_PART;
    float* Wt_pool = ws + OFF_WTPOOL;
    float* Wt_ge   = ws + OFF_WTG_E;
    float* Wt_gd   = ws + OFF_WTG_D;

    // ================= init: hs zero, imputation, weight transposes =================
    hs[gid] = 0.f;
    if (gid < 512) {
        float vx[8], vy[8];
        int fin = 0;
        for (int tt = 0; tt < 8; tt++) {
            float x = observed[tt * 1024 + gid * 2];
            float y = observed[tt * 1024 + gid * 2 + 1];
            vx[tt] = x; vy[tt] = y;
            if (isfinite(x) && isfinite(y)) fin |= (1 << tt);
        }
        int firstv = -1;
        for (int tt = 7; tt >= 0; tt--) if (fin & (1 << tt)) firstv = tt;
        int last = -1;
        for (int tt = 0; tt < 8; tt++) {
            if (fin & (1 << tt)) last = tt;
            int take = (last >= 0) ? last : firstv;
            float ox = 0.f, oy = 0.f;
            if (take >= 0) { ox = vx[take]; oy = vy[take]; }
            obs[tt * 1024 + gid * 2]     = ox;
            obs[tt * 1024 + gid * 2 + 1] = oy;
        }
    }
    {   // Wt_pool[k][p] = W_pool[p][k]; 65536 float4 tasks, one per thread
        int p = gid >> 9, k4 = gid & 511;
        float4 v = *(const float4*)(W_pool + p * 2048 + k4 * 4);
        float* dst = Wt_pool + (k4 * 4) * 128 + p;
        dst[0] = v.x; dst[128] = v.y; dst[256] = v.z; dst[384] = v.w;
    }
    for (int idx = gid; idx < 163840; idx += NBLK * NTHR) {
        int k = idx >> 9, o = idx & 511;
        float ve, vd;
        if (k < 192) { ve = Wih_e[o * 192 + k];       vd = Wih_d[o * 192 + k]; }
        else         { ve = Whh_e[o * 128 + k - 192]; vd = Whh_d[o * 128 + k - 192]; }
        Wt_ge[idx] = ve; Wt_gd[idx] = vd;
    }
    grid_barrier(bc, bg);

    const int rt = b >> 3, kc = b & 7, hc = kc;
    const int R0 = rt * 16;
    float cs_reg = 0.f;       // this thread's LSTM cell state (CD mapping: r=t>>4, hh=t&15)
    const int nstep = 7 + npred;

    for (int s = 0; s < nstep; s++) {
        const float* posp  = (s < 7) ? (obs + (s + 1) * 1024)
                                     : ((s == 7) ? (obs + 7 * 1024) : (out + (s - 8) * 1024));
        const float* prevp = (s < 7) ? (obs + s * 1024)
                                     : ((s <= 8) ? (obs + 7 * 1024) : (out + (s - 9) * 1024));
        const float* Wt_g = (s < 7) ? Wt_ge : Wt_gd;
        const float* bihp = (s < 7) ? bih_e : bih_d;
        const float* bhhp = (s < 7) ? bhh_e : bhh_d;

        // ================= Phase AB: pooling (2 cells) + emb + soc GEMM K-chunk =================
        {
            float* pos2 = (float*)smem_raw;                           // 1024 f
            int* cnt    = (int*)(smem_raw + 4096);                    // 32 i
            unsigned short* lst = (unsigned short*)(smem_raw + 4224); // 16*2*96 us
            float* AsT  = (float*)(smem_raw + 10368);                 // 256*20 f

            ((float4*)pos2)[t] = ((const float4*)posp)[t];
            if (t < 32) cnt[t] = 0;
            __syncthreads();

            if (kc == 0) {  // velocity embedding for own 16 agents
                int a = t >> 4, e4 = (t & 15) * 4;
                int i = R0 + a;
                float vx = pos2[2 * i]     - prevp[2 * i];
                float vy = pos2[2 * i + 1] - prevp[2 * i + 1];
                float4 r;
                r.x = fmaxf(W_pos[(e4 + 0) * 2] * vx + W_pos[(e4 + 0) * 2 + 1] * vy + b_pos[e4 + 0], 0.f);
                r.y = fmaxf(W_pos[(e4 + 1) * 2] * vx + W_pos[(e4 + 1) * 2 + 1] * vy + b_pos[e4 + 1], 0.f);
                r.z = fmaxf(W_pos[(e4 + 2) * 2] * vx + W_pos[(e4 + 2) * 2 + 1] * vy + b_pos[e4 + 2], 0.f);
                r.w = fmaxf(W_pos[(e4 + 3) * 2] * vx + W_pos[(e4 + 3) * 2 + 1] * vy + b_pos[e4 + 3], 0.f);
                *(float4*)&emb[i * 64 + e4] = r;
            }
            if (kc == 1 && s >= 7 && t < 32) {  // init out row = pos + b_out (CD atomically adds dot)
                int a = t >> 1, c = t & 1, i = R0 + a;
                out[(s - 7) * 1024 + 2 * i + c] = pos2[2 * i + c] + b_out[c];
            }
            {   // pair eval: agent a = t>>4, j strided by 16 for bank-friendly LDS reads
                int a = t >> 4, i = R0 + a;
                float pix = pos2[2 * i], piy = pos2[2 * i + 1];
                int c0 = kc * 2;
                for (int jj = 0; jj < 32; jj++) {
                    int j = (t & 15) + jj * 16;
                    float dx = pos2[2 * j]     - pix;
                    float dy = pos2[2 * j + 1] - piy;
                    if (j != i && fabsf(dx) <= 1.0f && fabsf(dy) <= 1.0f) {
                        int gx = (int)floorf((dx + 1.0f) * 2.0f); gx = gx < 0 ? 0 : (gx > 3 ? 3 : gx);
                        int gy = (int)floorf((dy + 1.0f) * 2.0f); gy = gy < 0 ? 0 : (gy > 3 ? 3 : gy);
                        int cc = gx * 4 + gy - c0;
                        if (cc == 0 || cc == 1) {
                            int slot = atomicAdd(&cnt[a * 2 + cc], 1);
                            if (slot < 96) lst[(a * 2 + cc) * 96 + slot] = (unsigned short)j;
                        }
                    }
                }
            }
            __syncthreads();
            {   // cell max -> AsT[k][agent], h strided (h = hq + 16u) for bank-spread writes
                int a = t >> 4, hq = t & 15;
                for (int cc = 0; cc < 2; cc++) {
                    int len = cnt[a * 2 + cc]; if (len > 96) len = 96;
                    float m[8];
                    #pragma unroll
                    for (int u = 0; u < 8; u++) m[u] = -3.0e38f;
                    for (int e = 0; e < len; e++) {
                        int j = lst[(a * 2 + cc) * 96 + e];
                        const float* hr = hs + j * 128 + hq;
                        #pragma unroll
                        for (int u = 0; u < 8; u++) m[u] = fmaxf(m[u], hr[u * 16]);
                    }
                    #pragma unroll
                    for (int u = 0; u < 8; u++)
                        AsT[(cc * 128 + hq + u * 16) * 20 + a] = (len > 0) ? m[u] : 0.f;
                }
            }
            __syncthreads();
            {   // soc GEMM: 16r x 128o x K256, thread tile 8x8, ksplit 8
                int ks = t >> 5, rowg = (t >> 4) & 1, og = t & 15;
                float acc[8][8];
                #pragma unroll
                for (int r = 0; r < 8; r++)
                    #pragma unroll
                    for (int o = 0; o < 8; o++) acc[r][o] = 0.f;
                const float4* A4 = (const float4*)AsT;      // [256][5]
                const float4* W4 = (const float4*)Wt_pool;  // [2048][32]
                int kb = kc * 256 + ks * 32;
                #pragma unroll 4
                for (int kk = 0; kk < 32; kk++) {
                    int kl = ks * 32 + kk;
                    float4 a0 = A4[kl * 5 + rowg * 2];
                    float4 a1 = A4[kl * 5 + rowg * 2 + 1];
                    float4 w0 = W4[(kb + kk) * 32 + og * 2];
                    float4 w1 = W4[(kb + kk) * 32 + og * 2 + 1];
                    float ar[8] = {a0.x, a0.y, a0.z, a0.w, a1.x, a1.y, a1.z, a1.w};
                    float wo[8] = {w0.x, w0.y, w0.z, w0.w, w1.x, w1.y, w1.z, w1.w};
                    #pragma unroll
                    for (int r = 0; r < 8; r++)
                        #pragma unroll
                        for (int o = 0; o < 8; o++)
                            acc[r][o] = fmaf(ar[r], wo[o], acc[r][o]);
                }
                #pragma unroll
                for (int r = 0; r < 8; r++)
                    #pragma unroll
                    for (int o = 0; o < 8; o++)
                        acc[r][o] += __shfl_xor(acc[r][o], 32);   // pair ks within wave
                __syncthreads();                                   // AsT/lists dead
                float* red = (float*)smem_raw;                     // [4][2048]
                int w = t >> 6, lane = t & 63;
                if (lane < 32) {
                    #pragma unroll
                    for (int r = 0; r < 8; r++) {
                        int rl = rowg * 8 + r;
                        float4 lo = make_float4(acc[r][0], acc[r][1], acc[r][2], acc[r][3]);
                        float4 hi = make_float4(acc[r][4], acc[r][5], acc[r][6], acc[r][7]);
                        *(float4*)&red[w * 2048 + rl * 128 + og * 8]     = lo;
                        *(float4*)&red[w * 2048 + rl * 128 + og * 8 + 4] = hi;
                    }
                }
                __syncthreads();
                {
                    int rl = t >> 4, og2 = t & 15;
                    float4 s0 = make_float4(0, 0, 0, 0), s1 = make_float4(0, 0, 0, 0);
                    #pragma unroll
                    for (int w2 = 0; w2 < 4; w2++) {
                        const float* rp = red + w2 * 2048 + rl * 128 + og2 * 8;
                        float4 v0 = *(const float4*)rp;
                        float4 v1 = *(const float4*)(rp + 4);
                        s0.x += v0.x; s0.y += v0.y; s0.z += v0.z; s0.w += v0.w;
                        s1.x += v1.x; s1.y += v1.y; s1.z += v1.z; s1.w += v1.w;
                    }
                    float* pp = part + kc * 65536 + (R0 + rl) * 128 + og2 * 8;
                    *(float4*)pp = s0;
                    *(float4*)(pp + 4) = s1;
                }
            }
        }
        grid_barrier(bc, bg);

        // ================= Phase CD: gates GEMM (h-aligned) + pointwise LSTM =================
        {
            float* AsT = (float*)smem_raw;   // [320][20] floats
            {   // stage emb rows (k 0..63)
                int r = t >> 4, e4 = (t & 15) * 4;
                float4 v = *(const float4*)&emb[(R0 + r) * 64 + e4];
                AsT[(e4 + 0) * 20 + r] = v.x;
                AsT[(e4 + 1) * 20 + r] = v.y;
                AsT[(e4 + 2) * 20 + r] = v.z;
                AsT[(e4 + 3) * 20 + r] = v.w;
            }
            {   // stage soc rows (k 64..191): reduce part over kc + bias + relu
                int r = t >> 4, p8 = (t & 15) * 8;
                float sv[8] = {0, 0, 0, 0, 0, 0, 0, 0};
                for (int kc2 = 0; kc2 < 8; kc2++) {
                    const float* pp = part + kc2 * 65536 + (R0 + r) * 128 + p8;
                    float4 v0 = *(const float4*)pp;
                    float4 v1 = *(const float4*)(pp + 4);
                    sv[0] += v0.x; sv[1] += v0.y; sv[2] += v0.z; sv[3] += v0.w;
                    sv[4] += v1.x; sv[5] += v1.y; sv[6] += v1.z; sv[7] += v1.w;
                }
                #pragma unroll
                for (int u = 0; u < 8; u++)
                    AsT[(64 + p8 + u) * 20 + r] = fmaxf(sv[u] + b_pool[p8 + u], 0.f);
            }
            {   // stage hs rows (k 192..319)
                int r = t >> 4, h8 = (t & 15) * 8;
                const float* hp = hs + (R0 + r) * 128 + h8;
                float4 v0 = *(const float4*)hp;
                float4 v1 = *(const float4*)(hp + 4);
                AsT[(192 + h8 + 0) * 20 + r] = v0.x;
                AsT[(192 + h8 + 1) * 20 + r] = v0.y;
                AsT[(192 + h8 + 2) * 20 + r] = v0.z;
                AsT[(192 + h8 + 3) * 20 + r] = v0.w;
                AsT[(192 + h8 + 4) * 20 + r] = v1.x;
                AsT[(192 + h8 + 5) * 20 + r] = v1.y;
                AsT[(192 + h8 + 6) * 20 + r] = v1.z;
                AsT[(192 + h8 + 7) * 20 + r] = v1.w;
            }
            __syncthreads();
            // gates GEMM: 16r x 64o (4 gates x 16 h) x K320; tile 8x8, ksplit 16
            float acc[8][8];
            #pragma unroll
            for (int r = 0; r < 8; r++)
                #pragma unroll
                for (int o = 0; o < 8; o++) acc[r][o] = 0.f;
            {
                int ks = t >> 4, rowg = (t >> 3) & 1, og = t & 7;
                const float4* A4  = (const float4*)AsT;   // [320][5]
                const float4* Wg4 = (const float4*)Wt_g;  // [320][128]
                int gate0 = og >> 1, rem = (og & 1) * 8;
                int col4 = (gate0 * 128 + hc * 16 + rem) >> 2;
                #pragma unroll 4
                for (int kk = 0; kk < 20; kk++) {
                    int k = ks * 20 + kk;
                    float4 a0 = A4[k * 5 + rowg * 2];
                    float4 a1 = A4[k * 5 + rowg * 2 + 1];
                    float4 w0 = Wg4[k * 128 + col4];
                    float4 w1 = Wg4[k * 128 + col4 + 1];
                    float ar[8] = {a0.x, a0.y, a0.z, a0.w, a1.x, a1.y, a1.z, a1.w};
                    float wo[8] = {w0.x, w0.y, w0.z, w0.w, w1.x, w1.y, w1.z, w1.w};
                    #pragma unroll
                    for (int r = 0; r < 8; r++)
                        #pragma unroll
                        for (int o = 0; o < 8; o++)
                            acc[r][o] = fmaf(ar[r], wo[o], acc[r][o]);
                }
                #pragma unroll
                for (int r = 0; r < 8; r++)
                    #pragma unroll
                    for (int o = 0; o < 8; o++) {
                        acc[r][o] += __shfl_xor(acc[r][o], 16);
                        acc[r][o] += __shfl_xor(acc[r][o], 32);
                    }
                __syncthreads();               // AsT dead
                float* red = (float*)smem_raw; // [4][1024]
                int w = t >> 6, lane = t & 63;
                if (lane < 16) {
                    #pragma unroll
                    for (int r = 0; r < 8; r++) {
                        int rl = rowg * 8 + r;
                        float4 lo = make_float4(acc[r][0], acc[r][1], acc[r][2], acc[r][3]);
                        float4 hi = make_float4(acc[r][4], acc[r][5], acc[r][6], acc[r][7]);
                        *(float4*)&red[w * 1024 + rl * 64 + og * 8]     = lo;
                        *(float4*)&red[w * 1024 + rl * 64 + og * 8 + 4] = hi;
                    }
                }
            }
            __syncthreads();
            {   // pointwise LSTM: thread (rl, hh)
                float* red = (float*)smem_raw;
                int rl = t >> 4, hh = t & 15;
                float g4[4];
                #pragma unroll
                for (int q = 0; q < 4; q++) {
                    int ol = q * 16 + hh;
                    float v = red[rl * 64 + ol] + red[1024 + rl * 64 + ol]
                            + red[2048 + rl * 64 + ol] + red[3072 + rl * 64 + ol];
                    int colq = q * 128 + hc * 16 + hh;
                    g4[q] = v + bihp[colq] + bhhp[colq];
                }
                float si = sigm(g4[0]);
                float sf = sigm(g4[1]);
                float so = sigm(g4[3]);
                float c2 = sf * cs_reg + si * tanhf(g4[2]);
                float h2 = so * tanhf(c2);
                cs_reg = c2;
                int i = R0 + rl, h = hc * 16 + hh;
                hs[i * 128 + h] = h2;
                if (s >= 7) {
                    float v0 = W_out[h] * h2;
                    float v1 = W_out[128 + h] * h2;
                    v0 += __shfl_down(v0, 8); v0 += __shfl_down(v0, 4);
                    v0 += __shfl_down(v0, 2); v0 += __shfl_down(v0, 1);
                    v1 += __shfl_down(v1, 8); v1 += __shfl_down(v1, 4);
                    v1 += __shfl_down(v1, 2); v1 += __shfl_down(v1, 1);
                    if (hh == 0) {
                        atomicAdd(&out[(s - 7) * 1024 + 2 * i],     v0);
                        atomicAdd(&out[(s - 7) * 1024 + 2 * i + 1], v1);
                    }
                }
            }
        }
        grid_barrier(bc, bg);
    }
}

extern "C" void kernel_launch(void* const* d_in, const int* in_sizes, int n_in,
                              void* d_out, int out_size, void* d_ws, size_t ws_size,
                              hipStream_t stream) {
    const float* observed = (const float*)d_in[0];
    const float* W_pos    = (const float*)d_in[1];
    const float* b_pos    = (const float*)d_in[2];
    const float* W_pool   = (const float*)d_in[3];
    const float* b_pool   = (const float*)d_in[4];
    const float* Wih_e    = (const float*)d_in[5];
    const float* bih_e    = (const float*)d_in[6];
    const float* Whh_e    = (const float*)d_in[7];
    const float* bhh_e    = (const float*)d_in[8];
    const float* Wih_d    = (const float*)d_in[9];
    const float* bih_d    = (const float*)d_in[10];
    const float* Whh_d    = (const float*)d_in[11];
    const float* bhh_d    = (const float*)d_in[12];
    const float* W_out    = (const float*)d_in[13];
    const float* b_out    = (const float*)d_in[14];
    float* outp = (float*)d_out;
    float* wsp  = (float*)d_ws;
    int npred = out_size / 1024;

    hipMemsetAsync(d_ws, 0, 256, stream);   // barrier counters (ws poisoned 0xAA each call)

    social_lstm<<<NBLK, NTHR, LDS_BYTES, stream>>>(
        observed, W_pos, b_pos, W_pool, b_pool,
        Wih_e, bih_e, Whh_e, bhh_e,
        Wih_d, bih_d, Whh_d, bhh_d,
        W_out, b_out, outp, wsp, npred);
}

// Round 4
// 1895.566 us; speedup vs baseline: 1.2668x; 1.2668x over previous
//
#include <hip/hip_runtime.h>
#include <math.h>

#define NBLK 256
#define NTHR 256

// ---- ws layout ----
// uints [0..4095]: arrival flags (block b at index b*16, 64B apart); uint [4096]: gen
// floats from 4160:
#define OFF_OBS     4160        // 8192
#define OFF_HS      12352       // 65536
#define OFF_EMB     77888       // 32768
#define OFF_PART    110656      // 524288  (8 kc x 512 x 128)
#define OFF_WTPOOL  634944      // 262144  (Wt_pool [2048][128])
#define OFF_WTG_E   897088      // 163840  (Wt gates enc [320][512])
#define OFF_WTG_D   1060928     // 163840  (Wt gates dec [320][512])

#define LDS_BYTES 32768

// Contention-free grid barrier: parallel per-block release flags + single gen release.
// (Round-3's 256 serialized device-scope RMWs on one line cost ~55 us/barrier.)
__device__ __forceinline__ void grid_barrier(unsigned* flags, unsigned* gen, unsigned seq) {
    __syncthreads();
    if (blockIdx.x == 0) {
        if (threadIdx.x < 64) {
            #pragma unroll
            for (int q = 0; q < 4; q++) {
                int bb = threadIdx.x * 4 + q;
                if (bb != 0) {
                    while (__hip_atomic_load(&flags[bb * 16], __ATOMIC_ACQUIRE,
                                             __HIP_MEMORY_SCOPE_AGENT) != seq)
                        __builtin_amdgcn_s_sleep(1);
                }
            }
        }
        __syncthreads();
        if (threadIdx.x == 0)
            __hip_atomic_store(gen, seq, __ATOMIC_RELEASE, __HIP_MEMORY_SCOPE_AGENT);
    } else {
        if (threadIdx.x == 0) {
            __hip_atomic_store(&flags[blockIdx.x * 16], seq, __ATOMIC_RELEASE,
                               __HIP_MEMORY_SCOPE_AGENT);
            while (__hip_atomic_load(gen, __ATOMIC_ACQUIRE,
                                     __HIP_MEMORY_SCOPE_AGENT) != seq)
                __builtin_amdgcn_s_sleep(2);
        }
    }
    __syncthreads();
}

__device__ __forceinline__ float sigm(float x) { return 1.f / (1.f + expf(-x)); }

__global__ void __launch_bounds__(NTHR, 1) social_lstm(
    const float* __restrict__ observed,
    const float* __restrict__ W_pos, const float* __restrict__ b_pos,
    const float* __restrict__ W_pool, const float* __restrict__ b_pool,
    const float* __restrict__ Wih_e, const float* __restrict__ bih_e,
    const float* __restrict__ Whh_e, const float* __restrict__ bhh_e,
    const float* __restrict__ Wih_d, const float* __restrict__ bih_d,
    const float* __restrict__ Whh_d, const float* __restrict__ bhh_d,
    const float* __restrict__ W_out, const float* __restrict__ b_out,
    float* __restrict__ out, float* __restrict__ ws, int npred)
{
    extern __shared__ char smem_raw[];
    const int t = threadIdx.x, b = blockIdx.x;
    const int gid = b * NTHR + t;

    unsigned* flags = (unsigned*)ws;
    unsigned* gen   = flags + 4096;
    float* obs     = ws + OFF_OBS;
    float* hs      = ws + OFF_HS;
    float* emb     = ws + OFF_EMB;
    float* part    = ws + OFF_PART;
    float* Wt_pool = ws + OFF_WTPOOL;
    float* Wt_ge   = ws + OFF_WTG_E;
    float* Wt_gd   = ws + OFF_WTG_D;
    unsigned seq = 1;

    // ================= init: hs zero, imputation, weight transposes =================
    hs[gid] = 0.f;
    if (gid < 512) {
        float vx[8], vy[8];
        int fin = 0;
        for (int tt = 0; tt < 8; tt++) {
            float x = observed[tt * 1024 + gid * 2];
            float y = observed[tt * 1024 + gid * 2 + 1];
            vx[tt] = x; vy[tt] = y;
            if (isfinite(x) && isfinite(y)) fin |= (1 << tt);
        }
        int firstv = -1;
        for (int tt = 7; tt >= 0; tt--) if (fin & (1 << tt)) firstv = tt;
        int last = -1;
        for (int tt = 0; tt < 8; tt++) {
            if (fin & (1 << tt)) last = tt;
            int take = (last >= 0) ? last : firstv;
            float ox = 0.f, oy = 0.f;
            if (take >= 0) { ox = vx[take]; oy = vy[take]; }
            obs[tt * 1024 + gid * 2]     = ox;
            obs[tt * 1024 + gid * 2 + 1] = oy;
        }
    }
    {   // Wt_pool[k][p] = W_pool[p][k]
        int p = gid >> 9, k4 = gid & 511;
        float4 v = *(const float4*)(W_pool + p * 2048 + k4 * 4);
        float* dst = Wt_pool + (k4 * 4) * 128 + p;
        dst[0] = v.x; dst[128] = v.y; dst[256] = v.z; dst[384] = v.w;
    }
    for (int idx = gid; idx < 163840; idx += NBLK * NTHR) {
        int k = idx >> 9, o = idx & 511;
        float ve, vd;
        if (k < 192) { ve = Wih_e[o * 192 + k];       vd = Wih_d[o * 192 + k]; }
        else         { ve = Whh_e[o * 128 + k - 192]; vd = Whh_d[o * 128 + k - 192]; }
        Wt_ge[idx] = ve; Wt_gd[idx] = vd;
    }
    grid_barrier(flags, gen, seq++);

    const int rt = b >> 3, kc = b & 7, hc = kc;
    const int R0 = rt * 16;
    float cs_reg = 0.f;       // CD mapping: r=t>>4, hh=t&15
    const int nstep = 7 + npred;

    for (int s = 0; s < nstep; s++) {
        const float* posp  = (s < 7) ? (obs + (s + 1) * 1024)
                                     : ((s == 7) ? (obs + 7 * 1024) : (out + (s - 8) * 1024));
        const float* prevp = (s < 7) ? (obs + s * 1024)
                                     : ((s <= 8) ? (obs + 7 * 1024) : (out + (s - 9) * 1024));
        const float* Wt_g = (s < 7) ? Wt_ge : Wt_gd;
        const float* bihp = (s < 7) ? bih_e : bih_d;
        const float* bhhp = (s < 7) ? bhh_e : bhh_d;

        // ================= Phase AB: pooling (2 cells) + emb + soc GEMM K-chunk =================
        {
            float* pos2 = (float*)smem_raw;                           // 1024 f
            int* cnt    = (int*)(smem_raw + 4096);                    // 32 i
            unsigned short* lst = (unsigned short*)(smem_raw + 4224); // 16*2*96 us
            float* AsT  = (float*)(smem_raw + 10368);                 // 256*20 f

            ((float4*)pos2)[t] = ((const float4*)posp)[t];
            if (t < 32) cnt[t] = 0;
            __syncthreads();

            if (kc == 0) {  // velocity embedding for own 16 agents
                int a = t >> 4, e4 = (t & 15) * 4;
                int i = R0 + a;
                float vx = pos2[2 * i]     - prevp[2 * i];
                float vy = pos2[2 * i + 1] - prevp[2 * i + 1];
                float4 r;
                r.x = fmaxf(W_pos[(e4 + 0) * 2] * vx + W_pos[(e4 + 0) * 2 + 1] * vy + b_pos[e4 + 0], 0.f);
                r.y = fmaxf(W_pos[(e4 + 1) * 2] * vx + W_pos[(e4 + 1) * 2 + 1] * vy + b_pos[e4 + 1], 0.f);
                r.z = fmaxf(W_pos[(e4 + 2) * 2] * vx + W_pos[(e4 + 2) * 2 + 1] * vy + b_pos[e4 + 2], 0.f);
                r.w = fmaxf(W_pos[(e4 + 3) * 2] * vx + W_pos[(e4 + 3) * 2 + 1] * vy + b_pos[e4 + 3], 0.f);
                *(float4*)&emb[i * 64 + e4] = r;
            }
            if (kc == 1 && s >= 7 && t < 32) {  // init out row = pos + b_out
                int a = t >> 1, c = t & 1, i = R0 + a;
                out[(s - 7) * 1024 + 2 * i + c] = pos2[2 * i + c] + b_out[c];
            }
            {   // pair eval
                int a = t >> 4, i = R0 + a;
                float pix = pos2[2 * i], piy = pos2[2 * i + 1];
                int c0 = kc * 2;
                for (int jj = 0; jj < 32; jj++) {
                    int j = (t & 15) + jj * 16;
                    float dx = pos2[2 * j]     - pix;
                    float dy = pos2[2 * j + 1] - piy;
                    if (j != i && fabsf(dx) <= 1.0f && fabsf(dy) <= 1.0f) {
                        int gx = (int)floorf((dx + 1.0f) * 2.0f); gx = gx < 0 ? 0 : (gx > 3 ? 3 : gx);
                        int gy = (int)floorf((dy + 1.0f) * 2.0f); gy = gy < 0 ? 0 : (gy > 3 ? 3 : gy);
                        int cc = gx * 4 + gy - c0;
                        if (cc == 0 || cc == 1) {
                            int slot = atomicAdd(&cnt[a * 2 + cc], 1);
                            if (slot < 96) lst[(a * 2 + cc) * 96 + slot] = (unsigned short)j;
                        }
                    }
                }
            }
            __syncthreads();
            {   // cell max -> AsT[k][agent]
                int a = t >> 4, hq = t & 15;
                for (int cc = 0; cc < 2; cc++) {
                    int len = cnt[a * 2 + cc]; if (len > 96) len = 96;
                    float m[8];
                    #pragma unroll
                    for (int u = 0; u < 8; u++) m[u] = -3.0e38f;
                    for (int e = 0; e < len; e++) {
                        int j = lst[(a * 2 + cc) * 96 + e];
                        const float* hr = hs + j * 128 + hq;
                        #pragma unroll
                        for (int u = 0; u < 8; u++) m[u] = fmaxf(m[u], hr[u * 16]);
                    }
                    #pragma unroll
                    for (int u = 0; u < 8; u++)
                        AsT[(cc * 128 + hq + u * 16) * 20 + a] = (len > 0) ? m[u] : 0.f;
                }
            }
            __syncthreads();
            {   // soc GEMM: 16r x 128o x K256, tile 8x8, ksplit 8
                int ks = t >> 5, rowg = (t >> 4) & 1, og = t & 15;
                float acc[8][8];
                #pragma unroll
                for (int r = 0; r < 8; r++)
                    #pragma unroll
                    for (int o = 0; o < 8; o++) acc[r][o] = 0.f;
                const float4* A4 = (const float4*)AsT;      // [256][5]
                const float4* W4 = (const float4*)Wt_pool;  // [2048][32]
                int kb = kc * 256 + ks * 32;
                #pragma unroll 4
                for (int kk = 0; kk < 32; kk++) {
                    int kl = ks * 32 + kk;
                    float4 a0 = A4[kl * 5 + rowg * 2];
                    float4 a1 = A4[kl * 5 + rowg * 2 + 1];
                    float4 w0 = W4[(kb + kk) * 32 + og * 2];
                    float4 w1 = W4[(kb + kk) * 32 + og * 2 + 1];
                    float ar[8] = {a0.x, a0.y, a0.z, a0.w, a1.x, a1.y, a1.z, a1.w};
                    float wo[8] = {w0.x, w0.y, w0.z, w0.w, w1.x, w1.y, w1.z, w1.w};
                    #pragma unroll
                    for (int r = 0; r < 8; r++)
                        #pragma unroll
                        for (int o = 0; o < 8; o++)
                            acc[r][o] = fmaf(ar[r], wo[o], acc[r][o]);
                }
                #pragma unroll
                for (int r = 0; r < 8; r++)
                    #pragma unroll
                    for (int o = 0; o < 8; o++)
                        acc[r][o] += __shfl_xor(acc[r][o], 32);
                __syncthreads();
                float* red = (float*)smem_raw;                     // [4][2048]
                int w = t >> 6, lane = t & 63;
                if (lane < 32) {
                    #pragma unroll
                    for (int r = 0; r < 8; r++) {
                        int rl = rowg * 8 + r;
                        float4 lo = make_float4(acc[r][0], acc[r][1], acc[r][2], acc[r][3]);
                        float4 hi = make_float4(acc[r][4], acc[r][5], acc[r][6], acc[r][7]);
                        *(float4*)&red[w * 2048 + rl * 128 + og * 8]     = lo;
                        *(float4*)&red[w * 2048 + rl * 128 + og * 8 + 4] = hi;
                    }
                }
                __syncthreads();
                {
                    int rl = t >> 4, og2 = t & 15;
                    float4 s0 = make_float4(0, 0, 0, 0), s1 = make_float4(0, 0, 0, 0);
                    #pragma unroll
                    for (int w2 = 0; w2 < 4; w2++) {
                        const float* rp = red + w2 * 2048 + rl * 128 + og2 * 8;
                        float4 v0 = *(const float4*)rp;
                        float4 v1 = *(const float4*)(rp + 4);
                        s0.x += v0.x; s0.y += v0.y; s0.z += v0.z; s0.w += v0.w;
                        s1.x += v1.x; s1.y += v1.y; s1.z += v1.z; s1.w += v1.w;
                    }
                    float* pp = part + kc * 65536 + (R0 + rl) * 128 + og2 * 8;
                    *(float4*)pp = s0;
                    *(float4*)(pp + 4) = s1;
                }
            }
        }
        grid_barrier(flags, gen, seq++);

        // ================= Phase CD: gates GEMM (h-aligned) + pointwise LSTM =================
        {
            float* AsT = (float*)smem_raw;   // [320][20] floats
            {   // stage emb rows (k 0..63)
                int r = t >> 4, e4 = (t & 15) * 4;
                float4 v = *(const float4*)&emb[(R0 + r) * 64 + e4];
                AsT[(e4 + 0) * 20 + r] = v.x;
                AsT[(e4 + 1) * 20 + r] = v.y;
                AsT[(e4 + 2) * 20 + r] = v.z;
                AsT[(e4 + 3) * 20 + r] = v.w;
            }
            {   // stage soc rows (k 64..191): reduce part over kc + bias + relu
                int r = t >> 4, p8 = (t & 15) * 8;
                float sv[8] = {0, 0, 0, 0, 0, 0, 0, 0};
                for (int kc2 = 0; kc2 < 8; kc2++) {
                    const float* pp = part + kc2 * 65536 + (R0 + r) * 128 + p8;
                    float4 v0 = *(const float4*)pp;
                    float4 v1 = *(const float4*)(pp + 4);
                    sv[0] += v0.x; sv[1] += v0.y; sv[2] += v0.z; sv[3] += v0.w;
                    sv[4] += v1.x; sv[5] += v1.y; sv[6] += v1.z; sv[7] += v1.w;
                }
                #pragma unroll
                for (int u = 0; u < 8; u++)
                    AsT[(64 + p8 + u) * 20 + r] = fmaxf(sv[u] + b_pool[p8 + u], 0.f);
            }
            {   // stage hs rows (k 192..319)
                int r = t >> 4, h8 = (t & 15) * 8;
                const float* hp = hs + (R0 + r) * 128 + h8;
                float4 v0 = *(const float4*)hp;
                float4 v1 = *(const float4*)(hp + 4);
                AsT[(192 + h8 + 0) * 20 + r] = v0.x;
                AsT[(192 + h8 + 1) * 20 + r] = v0.y;
                AsT[(192 + h8 + 2) * 20 + r] = v0.z;
                AsT[(192 + h8 + 3) * 20 + r] = v0.w;
                AsT[(192 + h8 + 4) * 20 + r] = v1.x;
                AsT[(192 + h8 + 5) * 20 + r] = v1.y;
                AsT[(192 + h8 + 6) * 20 + r] = v1.z;
                AsT[(192 + h8 + 7) * 20 + r] = v1.w;
            }
            __syncthreads();
            float acc[8][8];
            #pragma unroll
            for (int r = 0; r < 8; r++)
                #pragma unroll
                for (int o = 0; o < 8; o++) acc[r][o] = 0.f;
            {
                int ks = t >> 4, rowg = (t >> 3) & 1, og = t & 7;
                const float4* A4  = (const float4*)AsT;   // [320][5]
                const float4* Wg4 = (const float4*)Wt_g;  // [320][128]
                int gate0 = og >> 1, rem = (og & 1) * 8;
                int col4 = (gate0 * 128 + hc * 16 + rem) >> 2;
                #pragma unroll 4
                for (int kk = 0; kk < 20; kk++) {
                    int k = ks * 20 + kk;
                    float4 a0 = A4[k * 5 + rowg * 2];
                    float4 a1 = A4[k * 5 + rowg * 2 + 1];
                    float4 w0 = Wg4[k * 128 + col4];
                    float4 w1 = Wg4[k * 128 + col4 + 1];
                    float ar[8] = {a0.x, a0.y, a0.z, a0.w, a1.x, a1.y, a1.z, a1.w};
                    float wo[8] = {w0.x, w0.y, w0.z, w0.w, w1.x, w1.y, w1.z, w1.w};
                    #pragma unroll
                    for (int r = 0; r < 8; r++)
                        #pragma unroll
                        for (int o = 0; o < 8; o++)
                            acc[r][o] = fmaf(ar[r], wo[o], acc[r][o]);
                }
                #pragma unroll
                for (int r = 0; r < 8; r++)
                    #pragma unroll
                    for (int o = 0; o < 8; o++) {
                        acc[r][o] += __shfl_xor(acc[r][o], 16);
                        acc[r][o] += __shfl_xor(acc[r][o], 32);
                    }
                __syncthreads();
                float* red = (float*)smem_raw; // [4][1024]
                int w = t >> 6, lane = t & 63;
                if (lane < 16) {
                    #pragma unroll
                    for (int r = 0; r < 8; r++) {
                        int rl = rowg * 8 + r;
                        float4 lo = make_float4(acc[r][0], acc[r][1], acc[r][2], acc[r][3]);
                        float4 hi = make_float4(acc[r][4], acc[r][5], acc[r][6], acc[r][7]);
                        *(float4*)&red[w * 1024 + rl * 64 + og * 8]     = lo;
                        *(float4*)&red[w * 1024 + rl * 64 + og * 8 + 4] = hi;
                    }
                }
            }
            __syncthreads();
            {   // pointwise LSTM
                float* red = (float*)smem_raw;
                int rl = t >> 4, hh = t & 15;
                float g4[4];
                #pragma unroll
                for (int q = 0; q < 4; q++) {
                    int ol = q * 16 + hh;
                    float v = red[rl * 64 + ol] + red[1024 + rl * 64 + ol]
                            + red[2048 + rl * 64 + ol] + red[3072 + rl * 64 + ol];
                    int colq = q * 128 + hc * 16 + hh;
                    g4[q] = v + bihp[colq] + bhhp[colq];
                }
                float si = sigm(g4[0]);
                float sf = sigm(g4[1]);
                float so = sigm(g4[3]);
                float c2 = sf * cs_reg + si * tanhf(g4[2]);
                float h2 = so * tanhf(c2);
                cs_reg = c2;
                int i = R0 + rl, h = hc * 16 + hh;
                hs[i * 128 + h] = h2;
                if (s >= 7) {
                    float v0 = W_out[h] * h2;
                    float v1 = W_out[128 + h] * h2;
                    v0 += __shfl_down(v0, 8); v0 += __shfl_down(v0, 4);
                    v0 += __shfl_down(v0, 2); v0 += __shfl_down(v0, 1);
                    v1 += __shfl_down(v1, 8); v1 += __shfl_down(v1, 4);
                    v1 += __shfl_down(v1, 2); v1 += __shfl_down(v1, 1);
                    if (hh == 0) {
                        atomicAdd(&out[(s - 7) * 1024 + 2 * i],     v0);
                        atomicAdd(&out[(s - 7) * 1024 + 2 * i + 1], v1);
                    }
                }
            }
        }
        grid_barrier(flags, gen, seq++);
    }
}

extern "C" void kernel_launch(void* const* d_in, const int* in_sizes, int n_in,
                              void* d_out, int out_size, void* d_ws, size_t ws_size,
                              hipStream_t stream) {
    const float* observed = (const float*)d_in[0];
    const float* W_pos    = (const float*)d_in[1];
    const float* b_pos    = (const float*)d_in[2];
    const float* W_pool   = (const float*)d_in[3];
    const float* b_pool   = (const float*)d_in[4];
    const float* Wih_e    = (const float*)d_in[5];
    const float* bih_e    = (const float*)d_in[6];
    const float* Whh_e    = (const float*)d_in[7];
    const float* bhh_e    = (const float*)d_in[8];
    const float* Wih_d    = (const float*)d_in[9];
    const float* bih_d    = (const float*)d_in[10];
    const float* Whh_d    = (const float*)d_in[11];
    const float* bhh_d    = (const float*)d_in[12];
    const float* W_out    = (const float*)d_in[13];
    const float* b_out    = (const float*)d_in[14];
    float* outp = (float*)d_out;
    float* wsp  = (float*)d_ws;
    int npred = out_size / 1024;

    // zero flags (16 KB) + gen
    hipMemsetAsync(d_ws, 0, 20480, stream);

    social_lstm<<<NBLK, NTHR, LDS_BYTES, stream>>>(
        observed, W_pos, b_pos, W_pool, b_pool,
        Wih_e, bih_e, Whh_e, bhh_e,
        Wih_d, bih_d, Whh_d, bhh_d,
        W_out, b_out, outp, wsp, npred);
}

// Round 5
// 1044.109 us; speedup vs baseline: 2.2998x; 1.8155x over previous
//
#include <hip/hip_runtime.h>
#include <math.h>

#define NBLK 256
#define NTHR 256

// ---- ws layout ----
// uints [0..4095]: arrival flags (block b at index b*16, 64B apart); uint [4096]: gen
// floats from 4160:
#define OFF_OBS     4160        // 8192
#define OFF_HS      12352       // 65536
#define OFF_EMB     77888       // 32768
#define OFF_PART    110656      // 524288  (8 kc x 512 x 128)
#define OFF_WTPOOL  634944      // 262144  (Wt_pool [2048][128])
#define OFF_WTG_E   897088      // 163840  (Wt gates enc [320][512])
#define OFF_WTG_D   1060928     // 163840  (Wt gates dec [320][512])

#define LDS_BYTES 32768

// Device-coherent (LLC) scalar access, bypassing the non-coherent XCD L2.
// RELAXED => no buffer_inv / buffer_wbl2 per access.
__device__ __forceinline__ float ld_cohere(const float* p) {
    return __hip_atomic_load(p, __ATOMIC_RELAXED, __HIP_MEMORY_SCOPE_AGENT);
}
__device__ __forceinline__ void st_cohere(float* p, float v) {
    __hip_atomic_store(p, v, __ATOMIC_RELAXED, __HIP_MEMORY_SCOPE_AGENT);
}

// Grid barrier. Steady state (ACQ=false): relaxed polls (NO L2 invalidation —
// round 4's acquire-polling invalidated L2 each iteration, evicting weights and
// making every phase fetch-latency-bound). Data crossing the barrier travels via
// ld_cohere/st_cohere, so no acquire fence is needed. Init (ACQ=true): full
// release/acquire fences so normally-stored init data (obs, weight transposes)
// becomes visible and can be read through L2 forever after.
template <bool ACQ>
__device__ __forceinline__ void grid_barrier(unsigned* flags, unsigned* gen, unsigned seq) {
    __syncthreads();   // drains each wave's vmem (HIP emits s_waitcnt vmcnt(0) before s_barrier)
    if (blockIdx.x == 0) {
        if (threadIdx.x < 64) {
            #pragma unroll
            for (int q = 0; q < 4; q++) {
                int bb = threadIdx.x * 4 + q;
                if (bb != 0) {
                    while (__hip_atomic_load(&flags[bb * 16], __ATOMIC_RELAXED,
                                             __HIP_MEMORY_SCOPE_AGENT) != seq)
                        __builtin_amdgcn_s_sleep(1);
                }
            }
        }
        __syncthreads();
        if (ACQ) {
            if (threadIdx.x == 0)
                __builtin_amdgcn_fence(__ATOMIC_ACQUIRE, "agent");
            __syncthreads();
        }
        if (threadIdx.x == 0)
            __hip_atomic_store(gen, seq, __ATOMIC_RELEASE, __HIP_MEMORY_SCOPE_AGENT);
    } else {
        if (threadIdx.x == 0) {
            __hip_atomic_store(&flags[blockIdx.x * 16], seq, __ATOMIC_RELEASE,
                               __HIP_MEMORY_SCOPE_AGENT);
            while (__hip_atomic_load(gen, __ATOMIC_RELAXED,
                                     __HIP_MEMORY_SCOPE_AGENT) != seq)
                __builtin_amdgcn_s_sleep(2);
            if (ACQ)
                __builtin_amdgcn_fence(__ATOMIC_ACQUIRE, "agent");
        }
        __syncthreads();
    }
    asm volatile("" ::: "memory");
}

__device__ __forceinline__ float sigm(float x) { return 1.f / (1.f + expf(-x)); }

__global__ void __launch_bounds__(NTHR, 1) social_lstm(
    const float* __restrict__ observed,
    const float* __restrict__ W_pos, const float* __restrict__ b_pos,
    const float* __restrict__ W_pool, const float* __restrict__ b_pool,
    const float* __restrict__ Wih_e, const float* __restrict__ bih_e,
    const float* __restrict__ Whh_e, const float* __restrict__ bhh_e,
    const float* __restrict__ Wih_d, const float* __restrict__ bih_d,
    const float* __restrict__ Whh_d, const float* __restrict__ bhh_d,
    const float* __restrict__ W_out, const float* __restrict__ b_out,
    float* __restrict__ out, float* __restrict__ ws, int npred)
{
    extern __shared__ char smem_raw[];
    const int t = threadIdx.x, b = blockIdx.x;
    const int gid = b * NTHR + t;

    unsigned* flags = (unsigned*)ws;
    unsigned* gen   = flags + 4096;
    float* obs     = ws + OFF_OBS;
    float* hs      = ws + OFF_HS;
    float* emb     = ws + OFF_EMB;
    float* part    = ws + OFF_PART;
    float* Wt_pool = ws + OFF_WTPOOL;
    float* Wt_ge   = ws + OFF_WTG_E;
    float* Wt_gd   = ws + OFF_WTG_D;
    unsigned seq = 1;

    // ================= init: hs zero, imputation, weight transposes =================
    hs[gid] = 0.f;
    if (gid < 512) {
        float vx[8], vy[8];
        int fin = 0;
        for (int tt = 0; tt < 8; tt++) {
            float x = observed[tt * 1024 + gid * 2];
            float y = observed[tt * 1024 + gid * 2 + 1];
            vx[tt] = x; vy[tt] = y;
            if (isfinite(x) && isfinite(y)) fin |= (1 << tt);
        }
        int firstv = -1;
        for (int tt = 7; tt >= 0; tt--) if (fin & (1 << tt)) firstv = tt;
        int last = -1;
        for (int tt = 0; tt < 8; tt++) {
            if (fin & (1 << tt)) last = tt;
            int take = (last >= 0) ? last : firstv;
            float ox = 0.f, oy = 0.f;
            if (take >= 0) { ox = vx[take]; oy = vy[take]; }
            obs[tt * 1024 + gid * 2]     = ox;
            obs[tt * 1024 + gid * 2 + 1] = oy;
        }
    }
    {   // Wt_pool[k][p] = W_pool[p][k]
        int p = gid >> 9, k4 = gid & 511;
        float4 v = *(const float4*)(W_pool + p * 2048 + k4 * 4);
        float* dst = Wt_pool + (k4 * 4) * 128 + p;
        dst[0] = v.x; dst[128] = v.y; dst[256] = v.z; dst[384] = v.w;
    }
    for (int idx = gid; idx < 163840; idx += NBLK * NTHR) {
        int k = idx >> 9, o = idx & 511;
        float ve, vd;
        if (k < 192) { ve = Wih_e[o * 192 + k];       vd = Wih_d[o * 192 + k]; }
        else         { ve = Whh_e[o * 128 + k - 192]; vd = Whh_d[o * 128 + k - 192]; }
        Wt_ge[idx] = ve; Wt_gd[idx] = vd;
    }
    grid_barrier<true>(flags, gen, seq++);   // full fences: flush+inv once

    const int rt = b >> 3, kc = b & 7, hc = kc;
    const int R0 = rt * 16;
    float cs_reg = 0.f;       // CD mapping: r=t>>4, hh=t&15
    const int nstep = 7 + npred;

    for (int s = 0; s < nstep; s++) {
        const float* posp  = (s < 7) ? (obs + (s + 1) * 1024)
                                     : ((s == 7) ? (obs + 7 * 1024) : (out + (s - 8) * 1024));
        const float* prevp = (s < 7) ? (obs + s * 1024)
                                     : ((s <= 8) ? (obs + 7 * 1024) : (out + (s - 9) * 1024));
        const float* Wt_g = (s < 7) ? Wt_ge : Wt_gd;
        const float* bihp = (s < 7) ? bih_e : bih_d;
        const float* bhhp = (s < 7) ? bhh_e : bhh_d;

        // ================= Phase AB: pooling (2 cells) + emb + soc GEMM K-chunk =================
        {
            float* pos2 = (float*)smem_raw;                           // 1024 f
            int* cnt    = (int*)(smem_raw + 4096);                    // 32 i
            unsigned short* lst = (unsigned short*)(smem_raw + 4224); // 16*2*96 us
            float* AsT  = (float*)(smem_raw + 10368);                 // 256*20 f

            for (int q = t; q < 1024; q += NTHR) pos2[q] = ld_cohere(posp + q);
            if (t < 32) cnt[t] = 0;
            __syncthreads();

            if (kc == 0) {  // velocity embedding for own 16 agents
                int a = t >> 4, e4 = (t & 15) * 4;
                int i = R0 + a;
                float vx = pos2[2 * i]     - ld_cohere(prevp + 2 * i);
                float vy = pos2[2 * i + 1] - ld_cohere(prevp + 2 * i + 1);
                float* ed = emb + i * 64 + e4;
                st_cohere(ed + 0, fmaxf(W_pos[(e4 + 0) * 2] * vx + W_pos[(e4 + 0) * 2 + 1] * vy + b_pos[e4 + 0], 0.f));
                st_cohere(ed + 1, fmaxf(W_pos[(e4 + 1) * 2] * vx + W_pos[(e4 + 1) * 2 + 1] * vy + b_pos[e4 + 1], 0.f));
                st_cohere(ed + 2, fmaxf(W_pos[(e4 + 2) * 2] * vx + W_pos[(e4 + 2) * 2 + 1] * vy + b_pos[e4 + 2], 0.f));
                st_cohere(ed + 3, fmaxf(W_pos[(e4 + 3) * 2] * vx + W_pos[(e4 + 3) * 2 + 1] * vy + b_pos[e4 + 3], 0.f));
            }
            if (kc == 1 && s >= 7 && t < 32) {  // init out row = pos + b_out
                int a = t >> 1, c = t & 1, i = R0 + a;
                st_cohere(out + (s - 7) * 1024 + 2 * i + c, pos2[2 * i + c] + b_out[c]);
            }
            {   // pair eval
                int a = t >> 4, i = R0 + a;
                float pix = pos2[2 * i], piy = pos2[2 * i + 1];
                int c0 = kc * 2;
                for (int jj = 0; jj < 32; jj++) {
                    int j = (t & 15) + jj * 16;
                    float dx = pos2[2 * j]     - pix;
                    float dy = pos2[2 * j + 1] - piy;
                    if (j != i && fabsf(dx) <= 1.0f && fabsf(dy) <= 1.0f) {
                        int gx = (int)floorf((dx + 1.0f) * 2.0f); gx = gx < 0 ? 0 : (gx > 3 ? 3 : gx);
                        int gy = (int)floorf((dy + 1.0f) * 2.0f); gy = gy < 0 ? 0 : (gy > 3 ? 3 : gy);
                        int cc = gx * 4 + gy - c0;
                        if (cc == 0 || cc == 1) {
                            int slot = atomicAdd(&cnt[a * 2 + cc], 1);
                            if (slot < 96) lst[(a * 2 + cc) * 96 + slot] = (unsigned short)j;
                        }
                    }
                }
            }
            __syncthreads();
            {   // cell max -> AsT[k][agent]  (hs via device-coherent loads)
                int a = t >> 4, hq = t & 15;
                for (int cc = 0; cc < 2; cc++) {
                    int len = cnt[a * 2 + cc]; if (len > 96) len = 96;
                    float m[8];
                    #pragma unroll
                    for (int u = 0; u < 8; u++) m[u] = -3.0e38f;
                    for (int e = 0; e < len; e++) {
                        int j = lst[(a * 2 + cc) * 96 + e];
                        const float* hr = hs + j * 128 + hq;
                        #pragma unroll
                        for (int u = 0; u < 8; u++) m[u] = fmaxf(m[u], ld_cohere(hr + u * 16));
                    }
                    #pragma unroll
                    for (int u = 0; u < 8; u++)
                        AsT[(cc * 128 + hq + u * 16) * 20 + a] = (len > 0) ? m[u] : 0.f;
                }
            }
            __syncthreads();
            {   // soc GEMM: 16r x 128o x K256, tile 8x8, ksplit 8 (W from warm L2)
                int ks = t >> 5, rowg = (t >> 4) & 1, og = t & 15;
                float acc[8][8];
                #pragma unroll
                for (int r = 0; r < 8; r++)
                    #pragma unroll
                    for (int o = 0; o < 8; o++) acc[r][o] = 0.f;
                const float4* A4 = (const float4*)AsT;      // [256][5]
                const float4* W4 = (const float4*)Wt_pool;  // [2048][32]
                int kb = kc * 256 + ks * 32;
                #pragma unroll 4
                for (int kk = 0; kk < 32; kk++) {
                    int kl = ks * 32 + kk;
                    float4 a0 = A4[kl * 5 + rowg * 2];
                    float4 a1 = A4[kl * 5 + rowg * 2 + 1];
                    float4 w0 = W4[(kb + kk) * 32 + og * 2];
                    float4 w1 = W4[(kb + kk) * 32 + og * 2 + 1];
                    float ar[8] = {a0.x, a0.y, a0.z, a0.w, a1.x, a1.y, a1.z, a1.w};
                    float wo[8] = {w0.x, w0.y, w0.z, w0.w, w1.x, w1.y, w1.z, w1.w};
                    #pragma unroll
                    for (int r = 0; r < 8; r++)
                        #pragma unroll
                        for (int o = 0; o < 8; o++)
                            acc[r][o] = fmaf(ar[r], wo[o], acc[r][o]);
                }
                #pragma unroll
                for (int r = 0; r < 8; r++)
                    #pragma unroll
                    for (int o = 0; o < 8; o++)
                        acc[r][o] += __shfl_xor(acc[r][o], 32);
                __syncthreads();
                float* red = (float*)smem_raw;                     // [4][2048]
                int w = t >> 6, lane = t & 63;
                if (lane < 32) {
                    #pragma unroll
                    for (int r = 0; r < 8; r++) {
                        int rl = rowg * 8 + r;
                        float4 lo = make_float4(acc[r][0], acc[r][1], acc[r][2], acc[r][3]);
                        float4 hi = make_float4(acc[r][4], acc[r][5], acc[r][6], acc[r][7]);
                        *(float4*)&red[w * 2048 + rl * 128 + og * 8]     = lo;
                        *(float4*)&red[w * 2048 + rl * 128 + og * 8 + 4] = hi;
                    }
                }
                __syncthreads();
                {
                    int rl = t >> 4, og2 = t & 15;
                    float sv[8] = {0, 0, 0, 0, 0, 0, 0, 0};
                    #pragma unroll
                    for (int w2 = 0; w2 < 4; w2++) {
                        const float* rp = red + w2 * 2048 + rl * 128 + og2 * 8;
                        #pragma unroll
                        for (int u = 0; u < 8; u++) sv[u] += rp[u];
                    }
                    float* pp = part + kc * 65536 + (R0 + rl) * 128 + og2 * 8;
                    #pragma unroll
                    for (int u = 0; u < 8; u++) st_cohere(pp + u, sv[u]);
                }
            }
        }
        grid_barrier<false>(flags, gen, seq++);

        // ================= Phase CD: gates GEMM (h-aligned) + pointwise LSTM =================
        {
            float* AsT = (float*)smem_raw;   // [320][20] floats
            {   // stage emb rows (k 0..63)
                int r = t >> 4, e4 = (t & 15) * 4;
                const float* ep = emb + (R0 + r) * 64 + e4;
                AsT[(e4 + 0) * 20 + r] = ld_cohere(ep + 0);
                AsT[(e4 + 1) * 20 + r] = ld_cohere(ep + 1);
                AsT[(e4 + 2) * 20 + r] = ld_cohere(ep + 2);
                AsT[(e4 + 3) * 20 + r] = ld_cohere(ep + 3);
            }
            {   // stage soc rows (k 64..191): reduce part over kc + bias + relu
                int r = t >> 4, p8 = (t & 15) * 8;
                float sv[8] = {0, 0, 0, 0, 0, 0, 0, 0};
                for (int kc2 = 0; kc2 < 8; kc2++) {
                    const float* pp = part + kc2 * 65536 + (R0 + r) * 128 + p8;
                    #pragma unroll
                    for (int u = 0; u < 8; u++) sv[u] += ld_cohere(pp + u);
                }
                #pragma unroll
                for (int u = 0; u < 8; u++)
                    AsT[(64 + p8 + u) * 20 + r] = fmaxf(sv[u] + b_pool[p8 + u], 0.f);
            }
            {   // stage hs rows (k 192..319)
                int r = t >> 4, h8 = (t & 15) * 8;
                const float* hp = hs + (R0 + r) * 128 + h8;
                #pragma unroll
                for (int u = 0; u < 8; u++)
                    AsT[(192 + h8 + u) * 20 + r] = ld_cohere(hp + u);
            }
            __syncthreads();
            float acc[8][8];
            #pragma unroll
            for (int r = 0; r < 8; r++)
                #pragma unroll
                for (int o = 0; o < 8; o++) acc[r][o] = 0.f;
            {
                int ks = t >> 4, rowg = (t >> 3) & 1, og = t & 7;
                const float4* A4  = (const float4*)AsT;   // [320][5]
                const float4* Wg4 = (const float4*)Wt_g;  // [320][128] (warm L2)
                int gate0 = og >> 1, rem = (og & 1) * 8;
                int col4 = (gate0 * 128 + hc * 16 + rem) >> 2;
                #pragma unroll 4
                for (int kk = 0; kk < 20; kk++) {
                    int k = ks * 20 + kk;
                    float4 a0 = A4[k * 5 + rowg * 2];
                    float4 a1 = A4[k * 5 + rowg * 2 + 1];
                    float4 w0 = Wg4[k * 128 + col4];
                    float4 w1 = Wg4[k * 128 + col4 + 1];
                    float ar[8] = {a0.x, a0.y, a0.z, a0.w, a1.x, a1.y, a1.z, a1.w};
                    float wo[8] = {w0.x, w0.y, w0.z, w0.w, w1.x, w1.y, w1.z, w1.w};
                    #pragma unroll
                    for (int r = 0; r < 8; r++)
                        #pragma unroll
                        for (int o = 0; o < 8; o++)
                            acc[r][o] = fmaf(ar[r], wo[o], acc[r][o]);
                }
                #pragma unroll
                for (int r = 0; r < 8; r++)
                    #pragma unroll
                    for (int o = 0; o < 8; o++) {
                        acc[r][o] += __shfl_xor(acc[r][o], 16);
                        acc[r][o] += __shfl_xor(acc[r][o], 32);
                    }
                __syncthreads();
                float* red = (float*)smem_raw; // [4][1024]
                int w = t >> 6, lane = t & 63;
                if (lane < 16) {
                    #pragma unroll
                    for (int r = 0; r < 8; r++) {
                        int rl = rowg * 8 + r;
                        float4 lo = make_float4(acc[r][0], acc[r][1], acc[r][2], acc[r][3]);
                        float4 hi = make_float4(acc[r][4], acc[r][5], acc[r][6], acc[r][7]);
                        *(float4*)&red[w * 1024 + rl * 64 + og * 8]     = lo;
                        *(float4*)&red[w * 1024 + rl * 64 + og * 8 + 4] = hi;
                    }
                }
            }
            __syncthreads();
            {   // pointwise LSTM
                float* red = (float*)smem_raw;
                int rl = t >> 4, hh = t & 15;
                float g4[4];
                #pragma unroll
                for (int q = 0; q < 4; q++) {
                    int ol = q * 16 + hh;
                    float v = red[rl * 64 + ol] + red[1024 + rl * 64 + ol]
                            + red[2048 + rl * 64 + ol] + red[3072 + rl * 64 + ol];
                    int colq = q * 128 + hc * 16 + hh;
                    g4[q] = v + bihp[colq] + bhhp[colq];
                }
                float si = sigm(g4[0]);
                float sf = sigm(g4[1]);
                float so = sigm(g4[3]);
                float c2 = sf * cs_reg + si * tanhf(g4[2]);
                float h2 = so * tanhf(c2);
                cs_reg = c2;
                int i = R0 + rl, h = hc * 16 + hh;
                st_cohere(hs + i * 128 + h, h2);
                if (s >= 7) {
                    float v0 = W_out[h] * h2;
                    float v1 = W_out[128 + h] * h2;
                    v0 += __shfl_down(v0, 8); v0 += __shfl_down(v0, 4);
                    v0 += __shfl_down(v0, 2); v0 += __shfl_down(v0, 1);
                    v1 += __shfl_down(v1, 8); v1 += __shfl_down(v1, 4);
                    v1 += __shfl_down(v1, 2); v1 += __shfl_down(v1, 1);
                    if (hh == 0) {
                        atomicAdd(&out[(s - 7) * 1024 + 2 * i],     v0);
                        atomicAdd(&out[(s - 7) * 1024 + 2 * i + 1], v1);
                    }
                }
            }
        }
        grid_barrier<false>(flags, gen, seq++);
    }
}

extern "C" void kernel_launch(void* const* d_in, const int* in_sizes, int n_in,
                              void* d_out, int out_size, void* d_ws, size_t ws_size,
                              hipStream_t stream) {
    const float* observed = (const float*)d_in[0];
    const float* W_pos    = (const float*)d_in[1];
    const float* b_pos    = (const float*)d_in[2];
    const float* W_pool   = (const float*)d_in[3];
    const float* b_pool   = (const float*)d_in[4];
    const float* Wih_e    = (const float*)d_in[5];
    const float* bih_e    = (const float*)d_in[6];
    const float* Whh_e    = (const float*)d_in[7];
    const float* bhh_e    = (const float*)d_in[8];
    const float* Wih_d    = (const float*)d_in[9];
    const float* bih_d    = (const float*)d_in[10];
    const float* Whh_d    = (const float*)d_in[11];
    const float* bhh_d    = (const float*)d_in[12];
    const float* W_out    = (const float*)d_in[13];
    const float* b_out    = (const float*)d_in[14];
    float* outp = (float*)d_out;
    float* wsp  = (float*)d_ws;
    int npred = out_size / 1024;

    // zero flags (16 KB) + gen
    hipMemsetAsync(d_ws, 0, 20480, stream);

    social_lstm<<<NBLK, NTHR, LDS_BYTES, stream>>>(
        observed, W_pos, b_pos, W_pool, b_pool,
        Wih_e, bih_e, Whh_e, bhh_e,
        Wih_d, bih_d, Whh_d, bhh_d,
        W_out, b_out, outp, wsp, npred);
}

// Round 6
// 944.150 us; speedup vs baseline: 2.5433x; 1.1059x over previous
//
#include <hip/hip_runtime.h>
#include <math.h>

#define NBLK 256
#define NTHR 256

// ---- ws layout ----
// uints [0..4095]: arrival flags (block b at index b*16, 64B apart); uint [4096]: gen
// floats from 4160:
#define OFF_OBS     4160        // 8192
#define OFF_HS      12352       // 65536
#define OFF_EMB     77888       // 32768
#define OFF_PART    110656      // 524288  (8 kc x 512 x 128)
#define OFF_WTPOOL  634944      // 262144  (Wt_pool [2048][128])
#define OFF_WTG_E   897088      // 163840  (Wt gates enc [320][512])
#define OFF_WTG_D   1060928     // 163840  (Wt gates dec [320][512])

#define LDS_BYTES 32768

// Grid barrier with ONE release fence (buffer_wbl2) before arrival and ONE
// acquire fence (buffer_inv) after exit. Polls are RELAXED (no cache ops per
// iteration — round 4's bug). All cross-block data uses normal cached
// loads/stores; the two fences per barrier provide cross-XCD coherence.
__device__ __forceinline__ void grid_barrier(unsigned* flags, unsigned* gen, unsigned seq) {
    __syncthreads();   // all waves drain vmem (stores visible in this XCD's L2)
    if (threadIdx.x == 0)
        __builtin_amdgcn_fence(__ATOMIC_RELEASE, "agent");   // wbl2: flush L2 -> LLC
    if (blockIdx.x == 0) {
        if (threadIdx.x < 64) {
            #pragma unroll
            for (int q = 0; q < 4; q++) {
                int bb = threadIdx.x * 4 + q;
                if (bb != 0) {
                    while (__hip_atomic_load(&flags[bb * 16], __ATOMIC_RELAXED,
                                             __HIP_MEMORY_SCOPE_AGENT) != seq)
                        __builtin_amdgcn_s_sleep(1);
                }
            }
        }
        __syncthreads();
        if (threadIdx.x == 0) {
            __hip_atomic_store(gen, seq, __ATOMIC_RELAXED, __HIP_MEMORY_SCOPE_AGENT);
            __builtin_amdgcn_fence(__ATOMIC_ACQUIRE, "agent");  // inv L1+L2
        }
    } else {
        if (threadIdx.x == 0) {
            __hip_atomic_store(&flags[blockIdx.x * 16], seq, __ATOMIC_RELAXED,
                               __HIP_MEMORY_SCOPE_AGENT);
            while (__hip_atomic_load(gen, __ATOMIC_RELAXED,
                                     __HIP_MEMORY_SCOPE_AGENT) != seq)
                __builtin_amdgcn_s_sleep(2);
            __builtin_amdgcn_fence(__ATOMIC_ACQUIRE, "agent");  // inv L1+L2
        }
    }
    __syncthreads();
}

__device__ __forceinline__ float sigm(float x) { return 1.f / (1.f + expf(-x)); }
__device__ __forceinline__ float4 max4(float4 a, float4 b) {
    return make_float4(fmaxf(a.x, b.x), fmaxf(a.y, b.y), fmaxf(a.z, b.z), fmaxf(a.w, b.w));
}

__global__ void __launch_bounds__(NTHR, 1) social_lstm(
    const float* __restrict__ observed,
    const float* __restrict__ W_pos, const float* __restrict__ b_pos,
    const float* __restrict__ W_pool, const float* __restrict__ b_pool,
    const float* __restrict__ Wih_e, const float* __restrict__ bih_e,
    const float* __restrict__ Whh_e, const float* __restrict__ bhh_e,
    const float* __restrict__ Wih_d, const float* __restrict__ bih_d,
    const float* __restrict__ Whh_d, const float* __restrict__ bhh_d,
    const float* __restrict__ W_out, const float* __restrict__ b_out,
    float* __restrict__ out, float* __restrict__ ws, int npred)
{
    extern __shared__ char smem_raw[];
    const int t = threadIdx.x, b = blockIdx.x;
    const int gid = b * NTHR + t;

    unsigned* flags = (unsigned*)ws;
    unsigned* gen   = flags + 4096;
    float* obs     = ws + OFF_OBS;
    float* hs      = ws + OFF_HS;
    float* emb     = ws + OFF_EMB;
    float* part    = ws + OFF_PART;
    float* Wt_pool = ws + OFF_WTPOOL;
    float* Wt_ge   = ws + OFF_WTG_E;
    float* Wt_gd   = ws + OFF_WTG_D;
    unsigned seq = 1;

    // ================= init: hs zero, imputation, weight transposes =================
    hs[gid] = 0.f;
    if (gid < 512) {
        float vx[8], vy[8];
        int fin = 0;
        for (int tt = 0; tt < 8; tt++) {
            float x = observed[tt * 1024 + gid * 2];
            float y = observed[tt * 1024 + gid * 2 + 1];
            vx[tt] = x; vy[tt] = y;
            if (isfinite(x) && isfinite(y)) fin |= (1 << tt);
        }
        int firstv = -1;
        for (int tt = 7; tt >= 0; tt--) if (fin & (1 << tt)) firstv = tt;
        int last = -1;
        for (int tt = 0; tt < 8; tt++) {
            if (fin & (1 << tt)) last = tt;
            int take = (last >= 0) ? last : firstv;
            float ox = 0.f, oy = 0.f;
            if (take >= 0) { ox = vx[take]; oy = vy[take]; }
            obs[tt * 1024 + gid * 2]     = ox;
            obs[tt * 1024 + gid * 2 + 1] = oy;
        }
    }
    {   // Wt_pool[k][p] = W_pool[p][k]
        int p = gid >> 9, k4 = gid & 511;
        float4 v = *(const float4*)(W_pool + p * 2048 + k4 * 4);
        float* dst = Wt_pool + (k4 * 4) * 128 + p;
        dst[0] = v.x; dst[128] = v.y; dst[256] = v.z; dst[384] = v.w;
    }
    for (int idx = gid; idx < 163840; idx += NBLK * NTHR) {
        int k = idx >> 9, o = idx & 511;
        float ve, vd;
        if (k < 192) { ve = Wih_e[o * 192 + k];       vd = Wih_d[o * 192 + k]; }
        else         { ve = Whh_e[o * 128 + k - 192]; vd = Whh_d[o * 128 + k - 192]; }
        Wt_ge[idx] = ve; Wt_gd[idx] = vd;
    }
    grid_barrier(flags, gen, seq++);

    const int rt = b >> 3, kc = b & 7, hc = kc;
    const int R0 = rt * 16;
    float cs_reg = 0.f;       // CD mapping: r=t>>4, hh=t&15
    const int nstep = 7 + npred;

    for (int s = 0; s < nstep; s++) {
        const float* posp  = (s < 7) ? (obs + (s + 1) * 1024)
                                     : ((s == 7) ? (obs + 7 * 1024) : (out + (s - 8) * 1024));
        const float* prevp = (s < 7) ? (obs + s * 1024)
                                     : ((s <= 8) ? (obs + 7 * 1024) : (out + (s - 9) * 1024));
        const float* Wt_g = (s < 7) ? Wt_ge : Wt_gd;
        const float* bihp = (s < 7) ? bih_e : bih_d;
        const float* bhhp = (s < 7) ? bhh_e : bhh_d;

        // ================= Phase AB: pooling (2 cells) + emb + soc GEMM K-chunk =================
        {
            float* pos2 = (float*)smem_raw;                           // 1024 f
            int* cnt    = (int*)(smem_raw + 4096);                    // 32 i
            unsigned short* lst = (unsigned short*)(smem_raw + 4224); // 16*2*96 us
            float* AsT  = (float*)(smem_raw + 10368);                 // 256*20 f

            ((float4*)pos2)[t] = ((const float4*)posp)[t];
            if (t < 32) cnt[t] = 0;
            __syncthreads();

            if (kc == 0) {  // velocity embedding for own 16 agents
                int a = t >> 4, e4 = (t & 15) * 4;
                int i = R0 + a;
                float vx = pos2[2 * i]     - prevp[2 * i];
                float vy = pos2[2 * i + 1] - prevp[2 * i + 1];
                float4 r;
                r.x = fmaxf(W_pos[(e4 + 0) * 2] * vx + W_pos[(e4 + 0) * 2 + 1] * vy + b_pos[e4 + 0], 0.f);
                r.y = fmaxf(W_pos[(e4 + 1) * 2] * vx + W_pos[(e4 + 1) * 2 + 1] * vy + b_pos[e4 + 1], 0.f);
                r.z = fmaxf(W_pos[(e4 + 2) * 2] * vx + W_pos[(e4 + 2) * 2 + 1] * vy + b_pos[e4 + 2], 0.f);
                r.w = fmaxf(W_pos[(e4 + 3) * 2] * vx + W_pos[(e4 + 3) * 2 + 1] * vy + b_pos[e4 + 3], 0.f);
                *(float4*)&emb[i * 64 + e4] = r;
            }
            if (kc == 1 && s >= 7 && t < 32) {  // init out row = pos + b_out (flushed at mid barrier, before CD atomics)
                int a = t >> 1, c = t & 1, i = R0 + a;
                out[(s - 7) * 1024 + 2 * i + c] = pos2[2 * i + c] + b_out[c];
            }
            {   // pair eval
                int a = t >> 4, i = R0 + a;
                float pix = pos2[2 * i], piy = pos2[2 * i + 1];
                int c0 = kc * 2;
                for (int jj = 0; jj < 32; jj++) {
                    int j = (t & 15) + jj * 16;
                    float dx = pos2[2 * j]     - pix;
                    float dy = pos2[2 * j + 1] - piy;
                    if (j != i && fabsf(dx) <= 1.0f && fabsf(dy) <= 1.0f) {
                        int gx = (int)floorf((dx + 1.0f) * 2.0f); gx = gx < 0 ? 0 : (gx > 3 ? 3 : gx);
                        int gy = (int)floorf((dy + 1.0f) * 2.0f); gy = gy < 0 ? 0 : (gy > 3 ? 3 : gy);
                        int cc = gx * 4 + gy - c0;
                        if (cc == 0 || cc == 1) {
                            int slot = atomicAdd(&cnt[a * 2 + cc], 1);
                            if (slot < 96) lst[(a * 2 + cc) * 96 + slot] = (unsigned short)j;
                        }
                    }
                }
            }
            __syncthreads();
            {   // cell max -> AsT[k][agent]; hs via cached float4 loads (L2-resident,
                // coherent because every barrier does wbl2/inv)
                int a = t >> 4, hq = t & 15;
                for (int cc = 0; cc < 2; cc++) {
                    int len = cnt[a * 2 + cc]; if (len > 96) len = 96;
                    float4 m0 = make_float4(-3.0e38f, -3.0e38f, -3.0e38f, -3.0e38f);
                    float4 m1 = m0;
                    for (int e = 0; e < len; e++) {
                        int j = lst[(a * 2 + cc) * 96 + e];
                        const float4* hr = (const float4*)(hs + j * 128 + hq * 8);
                        m0 = max4(m0, hr[0]);
                        m1 = max4(m1, hr[1]);
                    }
                    float mm[8] = {m0.x, m0.y, m0.z, m0.w, m1.x, m1.y, m1.z, m1.w};
                    #pragma unroll
                    for (int u = 0; u < 8; u++)
                        AsT[(cc * 128 + hq * 8 + u) * 20 + a] = (len > 0) ? mm[u] : 0.f;
                }
            }
            __syncthreads();
            {   // soc GEMM: 16r x 128o x K256, tile 8x8, ksplit 8 (W from warm L2)
                int ks = t >> 5, rowg = (t >> 4) & 1, og = t & 15;
                float acc[8][8];
                #pragma unroll
                for (int r = 0; r < 8; r++)
                    #pragma unroll
                    for (int o = 0; o < 8; o++) acc[r][o] = 0.f;
                const float4* A4 = (const float4*)AsT;      // [256][5]
                const float4* W4 = (const float4*)Wt_pool;  // [2048][32]
                int kb = kc * 256 + ks * 32;
                #pragma unroll 4
                for (int kk = 0; kk < 32; kk++) {
                    int kl = ks * 32 + kk;
                    float4 a0 = A4[kl * 5 + rowg * 2];
                    float4 a1 = A4[kl * 5 + rowg * 2 + 1];
                    float4 w0 = W4[(kb + kk) * 32 + og * 2];
                    float4 w1 = W4[(kb + kk) * 32 + og * 2 + 1];
                    float ar[8] = {a0.x, a0.y, a0.z, a0.w, a1.x, a1.y, a1.z, a1.w};
                    float wo[8] = {w0.x, w0.y, w0.z, w0.w, w1.x, w1.y, w1.z, w1.w};
                    #pragma unroll
                    for (int r = 0; r < 8; r++)
                        #pragma unroll
                        for (int o = 0; o < 8; o++)
                            acc[r][o] = fmaf(ar[r], wo[o], acc[r][o]);
                }
                #pragma unroll
                for (int r = 0; r < 8; r++)
                    #pragma unroll
                    for (int o = 0; o < 8; o++)
                        acc[r][o] += __shfl_xor(acc[r][o], 32);
                __syncthreads();
                float* red = (float*)smem_raw;                     // [4][2048]
                int w = t >> 6, lane = t & 63;
                if (lane < 32) {
                    #pragma unroll
                    for (int r = 0; r < 8; r++) {
                        int rl = rowg * 8 + r;
                        float4 lo = make_float4(acc[r][0], acc[r][1], acc[r][2], acc[r][3]);
                        float4 hi = make_float4(acc[r][4], acc[r][5], acc[r][6], acc[r][7]);
                        *(float4*)&red[w * 2048 + rl * 128 + og * 8]     = lo;
                        *(float4*)&red[w * 2048 + rl * 128 + og * 8 + 4] = hi;
                    }
                }
                __syncthreads();
                {
                    int rl = t >> 4, og2 = t & 15;
                    float4 s0 = make_float4(0, 0, 0, 0), s1 = make_float4(0, 0, 0, 0);
                    #pragma unroll
                    for (int w2 = 0; w2 < 4; w2++) {
                        const float* rp = red + w2 * 2048 + rl * 128 + og2 * 8;
                        float4 v0 = *(const float4*)rp;
                        float4 v1 = *(const float4*)(rp + 4);
                        s0.x += v0.x; s0.y += v0.y; s0.z += v0.z; s0.w += v0.w;
                        s1.x += v1.x; s1.y += v1.y; s1.z += v1.z; s1.w += v1.w;
                    }
                    float* pp = part + kc * 65536 + (R0 + rl) * 128 + og2 * 8;
                    *(float4*)pp = s0;          // cached write-back; flushed by mid-barrier wbl2
                    *(float4*)(pp + 4) = s1;
                }
            }
        }
        grid_barrier(flags, gen, seq++);

        // ================= Phase CD: gates GEMM (h-aligned) + pointwise LSTM =================
        {
            float* AsT = (float*)smem_raw;   // [320][20] floats
            {   // stage emb rows (k 0..63)
                int r = t >> 4, e4 = (t & 15) * 4;
                float4 v = *(const float4*)&emb[(R0 + r) * 64 + e4];
                AsT[(e4 + 0) * 20 + r] = v.x;
                AsT[(e4 + 1) * 20 + r] = v.y;
                AsT[(e4 + 2) * 20 + r] = v.z;
                AsT[(e4 + 3) * 20 + r] = v.w;
            }
            {   // stage soc rows (k 64..191): reduce part over kc + bias + relu
                int r = t >> 4, p8 = (t & 15) * 8;
                float sv[8] = {0, 0, 0, 0, 0, 0, 0, 0};
                for (int kc2 = 0; kc2 < 8; kc2++) {
                    const float* pp = part + kc2 * 65536 + (R0 + r) * 128 + p8;
                    float4 v0 = *(const float4*)pp;
                    float4 v1 = *(const float4*)(pp + 4);
                    sv[0] += v0.x; sv[1] += v0.y; sv[2] += v0.z; sv[3] += v0.w;
                    sv[4] += v1.x; sv[5] += v1.y; sv[6] += v1.z; sv[7] += v1.w;
                }
                #pragma unroll
                for (int u = 0; u < 8; u++)
                    AsT[(64 + p8 + u) * 20 + r] = fmaxf(sv[u] + b_pool[p8 + u], 0.f);
            }
            {   // stage hs rows (k 192..319)
                int r = t >> 4, h8 = (t & 15) * 8;
                const float* hp = hs + (R0 + r) * 128 + h8;
                float4 v0 = *(const float4*)hp;
                float4 v1 = *(const float4*)(hp + 4);
                AsT[(192 + h8 + 0) * 20 + r] = v0.x;
                AsT[(192 + h8 + 1) * 20 + r] = v0.y;
                AsT[(192 + h8 + 2) * 20 + r] = v0.z;
                AsT[(192 + h8 + 3) * 20 + r] = v0.w;
                AsT[(192 + h8 + 4) * 20 + r] = v1.x;
                AsT[(192 + h8 + 5) * 20 + r] = v1.y;
                AsT[(192 + h8 + 6) * 20 + r] = v1.z;
                AsT[(192 + h8 + 7) * 20 + r] = v1.w;
            }
            __syncthreads();
            float acc[8][8];
            #pragma unroll
            for (int r = 0; r < 8; r++)
                #pragma unroll
                for (int o = 0; o < 8; o++) acc[r][o] = 0.f;
            {
                int ks = t >> 4, rowg = (t >> 3) & 1, og = t & 7;
                const float4* A4  = (const float4*)AsT;   // [320][5]
                const float4* Wg4 = (const float4*)Wt_g;  // [320][128] (warm L2)
                int gate0 = og >> 1, rem = (og & 1) * 8;
                int col4 = (gate0 * 128 + hc * 16 + rem) >> 2;
                #pragma unroll 4
                for (int kk = 0; kk < 20; kk++) {
                    int k = ks * 20 + kk;
                    float4 a0 = A4[k * 5 + rowg * 2];
                    float4 a1 = A4[k * 5 + rowg * 2 + 1];
                    float4 w0 = Wg4[k * 128 + col4];
                    float4 w1 = Wg4[k * 128 + col4 + 1];
                    float ar[8] = {a0.x, a0.y, a0.z, a0.w, a1.x, a1.y, a1.z, a1.w};
                    float wo[8] = {w0.x, w0.y, w0.z, w0.w, w1.x, w1.y, w1.z, w1.w};
                    #pragma unroll
                    for (int r = 0; r < 8; r++)
                        #pragma unroll
                        for (int o = 0; o < 8; o++)
                            acc[r][o] = fmaf(ar[r], wo[o], acc[r][o]);
                }
                #pragma unroll
                for (int r = 0; r < 8; r++)
                    #pragma unroll
                    for (int o = 0; o < 8; o++) {
                        acc[r][o] += __shfl_xor(acc[r][o], 16);
                        acc[r][o] += __shfl_xor(acc[r][o], 32);
                    }
                __syncthreads();
                float* red = (float*)smem_raw; // [4][1024]
                int w = t >> 6, lane = t & 63;
                if (lane < 16) {
                    #pragma unroll
                    for (int r = 0; r < 8; r++) {
                        int rl = rowg * 8 + r;
                        float4 lo = make_float4(acc[r][0], acc[r][1], acc[r][2], acc[r][3]);
                        float4 hi = make_float4(acc[r][4], acc[r][5], acc[r][6], acc[r][7]);
                        *(float4*)&red[w * 1024 + rl * 64 + og * 8]     = lo;
                        *(float4*)&red[w * 1024 + rl * 64 + og * 8 + 4] = hi;
                    }
                }
            }
            __syncthreads();
            {   // pointwise LSTM
                float* red = (float*)smem_raw;
                int rl = t >> 4, hh = t & 15;
                float g4[4];
                #pragma unroll
                for (int q = 0; q < 4; q++) {
                    int ol = q * 16 + hh;
                    float v = red[rl * 64 + ol] + red[1024 + rl * 64 + ol]
                            + red[2048 + rl * 64 + ol] + red[3072 + rl * 64 + ol];
                    int colq = q * 128 + hc * 16 + hh;
                    g4[q] = v + bihp[colq] + bhhp[colq];
                }
                float si = sigm(g4[0]);
                float sf = sigm(g4[1]);
                float so = sigm(g4[3]);
                float c2 = sf * cs_reg + si * tanhf(g4[2]);
                float h2 = so * tanhf(c2);
                cs_reg = c2;
                int i = R0 + rl, h = hc * 16 + hh;
                hs[i * 128 + h] = h2;   // cached; flushed at end-step barrier
                if (s >= 7) {
                    float v0 = W_out[h] * h2;
                    float v1 = W_out[128 + h] * h2;
                    v0 += __shfl_down(v0, 8); v0 += __shfl_down(v0, 4);
                    v0 += __shfl_down(v0, 2); v0 += __shfl_down(v0, 1);
                    v1 += __shfl_down(v1, 8); v1 += __shfl_down(v1, 4);
                    v1 += __shfl_down(v1, 2); v1 += __shfl_down(v1, 1);
                    if (hh == 0) {
                        atomicAdd(&out[(s - 7) * 1024 + 2 * i],     v0);
                        atomicAdd(&out[(s - 7) * 1024 + 2 * i + 1], v1);
                    }
                }
            }
        }
        grid_barrier(flags, gen, seq++);
    }
}

extern "C" void kernel_launch(void* const* d_in, const int* in_sizes, int n_in,
                              void* d_out, int out_size, void* d_ws, size_t ws_size,
                              hipStream_t stream) {
    const float* observed = (const float*)d_in[0];
    const float* W_pos    = (const float*)d_in[1];
    const float* b_pos    = (const float*)d_in[2];
    const float* W_pool   = (const float*)d_in[3];
    const float* b_pool   = (const float*)d_in[4];
    const float* Wih_e    = (const float*)d_in[5];
    const float* bih_e    = (const float*)d_in[6];
    const float* Whh_e    = (const float*)d_in[7];
    const float* bhh_e    = (const float*)d_in[8];
    const float* Wih_d    = (const float*)d_in[9];
    const float* bih_d    = (const float*)d_in[10];
    const float* Whh_d    = (const float*)d_in[11];
    const float* bhh_d    = (const float*)d_in[12];
    const float* W_out    = (const float*)d_in[13];
    const float* b_out    = (const float*)d_in[14];
    float* outp = (float*)d_out;
    float* wsp  = (float*)d_ws;
    int npred = out_size / 1024;

    // zero flags (16 KB) + gen
    hipMemsetAsync(d_ws, 0, 20480, stream);

    social_lstm<<<NBLK, NTHR, LDS_BYTES, stream>>>(
        observed, W_pos, b_pos, W_pool, b_pool,
        Wih_e, bih_e, Whh_e, bhh_e,
        Wih_d, bih_d, Whh_d, bhh_d,
        W_out, b_out, outp, wsp, npred);
}

// Round 7
// 911.585 us; speedup vs baseline: 2.6341x; 1.0357x over previous
//
#include <hip/hip_runtime.h>
#include <math.h>

#define NBLK 256
#define NTHR 512

// ---- ws layout ----
// uints [0..4095]: arrival flags (block b at index b*16, 64B apart); uint [4096]: gen
// floats from 4160:
#define OFF_OBS     4160        // 8192
#define OFF_HS      12352       // 65536
#define OFF_EMB     77888       // 32768
#define OFF_PART    110656      // 524288  (8 kc x 512 x 128)
#define OFF_WTPOOL  634944      // 262144  (Wt_pool [2048][128])
#define OFF_WTG_E   897088      // 163840  (Wt gates enc [320][512])
#define OFF_WTG_D   1060928     // 163840  (Wt gates dec [320][512])

#define LDS_BYTES 30848

// Grid barrier: ONE release fence (wbl2) before arrival, ONE acquire fence (inv)
// after exit; RELAXED polls (no cache ops per poll iteration).
__device__ __forceinline__ void grid_barrier(unsigned* flags, unsigned* gen, unsigned seq) {
    __syncthreads();
    if (threadIdx.x == 0)
        __builtin_amdgcn_fence(__ATOMIC_RELEASE, "agent");   // wbl2
    if (blockIdx.x == 0) {
        if (threadIdx.x < 64) {
            #pragma unroll
            for (int q = 0; q < 4; q++) {
                int bb = threadIdx.x * 4 + q;
                if (bb != 0) {
                    while (__hip_atomic_load(&flags[bb * 16], __ATOMIC_RELAXED,
                                             __HIP_MEMORY_SCOPE_AGENT) != seq)
                        __builtin_amdgcn_s_sleep(1);
                }
            }
        }
        __syncthreads();
        if (threadIdx.x == 0) {
            __hip_atomic_store(gen, seq, __ATOMIC_RELAXED, __HIP_MEMORY_SCOPE_AGENT);
            __builtin_amdgcn_fence(__ATOMIC_ACQUIRE, "agent");  // inv
        }
    } else {
        if (threadIdx.x == 0) {
            __hip_atomic_store(&flags[blockIdx.x * 16], seq, __ATOMIC_RELAXED,
                               __HIP_MEMORY_SCOPE_AGENT);
            while (__hip_atomic_load(gen, __ATOMIC_RELAXED,
                                     __HIP_MEMORY_SCOPE_AGENT) != seq)
                __builtin_amdgcn_s_sleep(2);
            __builtin_amdgcn_fence(__ATOMIC_ACQUIRE, "agent");  // inv
        }
    }
    __syncthreads();
}

__device__ __forceinline__ float sigm(float x) { return 1.f / (1.f + expf(-x)); }
__device__ __forceinline__ float4 max4(float4 a, float4 b) {
    return make_float4(fmaxf(a.x, b.x), fmaxf(a.y, b.y), fmaxf(a.z, b.z), fmaxf(a.w, b.w));
}

__global__ void __launch_bounds__(NTHR, 1) social_lstm(
    const float* __restrict__ observed,
    const float* __restrict__ W_pos, const float* __restrict__ b_pos,
    const float* __restrict__ W_pool, const float* __restrict__ b_pool,
    const float* __restrict__ Wih_e, const float* __restrict__ bih_e,
    const float* __restrict__ Whh_e, const float* __restrict__ bhh_e,
    const float* __restrict__ Wih_d, const float* __restrict__ bih_d,
    const float* __restrict__ Whh_d, const float* __restrict__ bhh_d,
    const float* __restrict__ W_out, const float* __restrict__ b_out,
    float* __restrict__ out, float* __restrict__ ws, int npred)
{
    extern __shared__ char smem_raw[];
    const int t = threadIdx.x, b = blockIdx.x;
    const int gid = b * NTHR + t;   // 0..131071

    unsigned* flags = (unsigned*)ws;
    unsigned* gen   = flags + 4096;
    float* obs     = ws + OFF_OBS;
    float* hs      = ws + OFF_HS;
    float* emb     = ws + OFF_EMB;
    float* part    = ws + OFF_PART;
    float* Wt_pool = ws + OFF_WTPOOL;
    float* Wt_ge   = ws + OFF_WTG_E;
    float* Wt_gd   = ws + OFF_WTG_D;
    unsigned seq = 1;

    // ================= init: hs zero, imputation, weight transposes =================
    if (gid < 65536) hs[gid] = 0.f;
    if (gid < 512) {
        float vx[8], vy[8];
        int fin = 0;
        for (int tt = 0; tt < 8; tt++) {
            float x = observed[tt * 1024 + gid * 2];
            float y = observed[tt * 1024 + gid * 2 + 1];
            vx[tt] = x; vy[tt] = y;
            if (isfinite(x) && isfinite(y)) fin |= (1 << tt);
        }
        int firstv = -1;
        for (int tt = 7; tt >= 0; tt--) if (fin & (1 << tt)) firstv = tt;
        int last = -1;
        for (int tt = 0; tt < 8; tt++) {
            if (fin & (1 << tt)) last = tt;
            int take = (last >= 0) ? last : firstv;
            float ox = 0.f, oy = 0.f;
            if (take >= 0) { ox = vx[take]; oy = vy[take]; }
            obs[tt * 1024 + gid * 2]     = ox;
            obs[tt * 1024 + gid * 2 + 1] = oy;
        }
    }
    if (gid < 65536) {   // Wt_pool[k][p] = W_pool[p][k]
        int p = gid >> 9, k4 = gid & 511;
        float4 v = *(const float4*)(W_pool + p * 2048 + k4 * 4);
        float* dst = Wt_pool + (k4 * 4) * 128 + p;
        dst[0] = v.x; dst[128] = v.y; dst[256] = v.z; dst[384] = v.w;
    }
    for (int idx = gid; idx < 163840; idx += NBLK * NTHR) {
        int k = idx >> 9, o = idx & 511;
        float ve, vd;
        if (k < 192) { ve = Wih_e[o * 192 + k];       vd = Wih_d[o * 192 + k]; }
        else         { ve = Whh_e[o * 128 + k - 192]; vd = Whh_d[o * 128 + k - 192]; }
        Wt_ge[idx] = ve; Wt_gd[idx] = vd;
    }
    grid_barrier(flags, gen, seq++);

    const int rt = b >> 3, kc = b & 7, hc = kc;
    const int R0 = rt * 16;
    float cs_reg = 0.f;       // valid in threads t<256: rl=t>>4, hh=t&15
    const int nstep = 7 + npred;

    for (int s = 0; s < nstep; s++) {
        const float* posp  = (s < 7) ? (obs + (s + 1) * 1024)
                                     : ((s == 7) ? (obs + 7 * 1024) : (out + (s - 8) * 1024));
        const float* prevp = (s < 7) ? (obs + s * 1024)
                                     : ((s <= 8) ? (obs + 7 * 1024) : (out + (s - 9) * 1024));
        const float* Wt_g = (s < 7) ? Wt_ge : Wt_gd;
        const float* bihp = (s < 7) ? bih_e : bih_d;
        const float* bhhp = (s < 7) ? bhh_e : bhh_d;

        // ===== Phase AB: pooling (2 cells) + emb + soc GEMM K-chunk =====
        {
            float* pos2 = (float*)smem_raw;                           // 1024 f
            int* cnt    = (int*)(smem_raw + 4096);                    // 32 i
            unsigned short* lst = (unsigned short*)(smem_raw + 4224); // 32*96 us
            float* AsT  = (float*)(smem_raw + 10368);                 // 256*20 f

            if (t < 256) ((float4*)pos2)[t] = ((const float4*)posp)[t];
            if (t < 32) cnt[t] = 0;
            __syncthreads();

            if (kc == 0 && t < 256) {  // velocity embedding for own 16 agents
                int a = t >> 4, e4 = (t & 15) * 4;
                int i = R0 + a;
                float vx = pos2[2 * i]     - prevp[2 * i];
                float vy = pos2[2 * i + 1] - prevp[2 * i + 1];
                float4 r;
                r.x = fmaxf(W_pos[(e4 + 0) * 2] * vx + W_pos[(e4 + 0) * 2 + 1] * vy + b_pos[e4 + 0], 0.f);
                r.y = fmaxf(W_pos[(e4 + 1) * 2] * vx + W_pos[(e4 + 1) * 2 + 1] * vy + b_pos[e4 + 1], 0.f);
                r.z = fmaxf(W_pos[(e4 + 2) * 2] * vx + W_pos[(e4 + 2) * 2 + 1] * vy + b_pos[e4 + 2], 0.f);
                r.w = fmaxf(W_pos[(e4 + 3) * 2] * vx + W_pos[(e4 + 3) * 2 + 1] * vy + b_pos[e4 + 3], 0.f);
                *(float4*)&emb[i * 64 + e4] = r;
            }
            if (kc == 1 && s >= 7 && t < 32) {  // init out row = pos + b_out
                int a = t >> 1, c = t & 1, i = R0 + a;
                out[(s - 7) * 1024 + 2 * i + c] = pos2[2 * i + c] + b_out[c];
            }
            {   // pair eval: agent a = t>>5, 32 threads/agent, 16 j each
                int a = t >> 5, i = R0 + a;
                float pix = pos2[2 * i], piy = pos2[2 * i + 1];
                int c0 = kc * 2;
                for (int jj = 0; jj < 16; jj++) {
                    int j = (t & 31) + jj * 32;
                    float dx = pos2[2 * j]     - pix;
                    float dy = pos2[2 * j + 1] - piy;
                    if (j != i && fabsf(dx) <= 1.0f && fabsf(dy) <= 1.0f) {
                        int gx = (int)floorf((dx + 1.0f) * 2.0f); gx = gx < 0 ? 0 : (gx > 3 ? 3 : gx);
                        int gy = (int)floorf((dy + 1.0f) * 2.0f); gy = gy < 0 ? 0 : (gy > 3 ? 3 : gy);
                        int cc = gx * 4 + gy - c0;
                        if (cc == 0 || cc == 1) {
                            int slot = atomicAdd(&cnt[a * 2 + cc], 1);
                            if (slot < 96) lst[(a * 2 + cc) * 96 + slot] = (unsigned short)j;
                        }
                    }
                }
            }
            __syncthreads();
            {   // cell max -> AsT[k][agent]: thread = (a, cc, hq)
                int a = t >> 5, cc = (t >> 4) & 1, hq = t & 15;
                int len = cnt[a * 2 + cc]; if (len > 96) len = 96;
                float4 m0 = make_float4(-3.0e38f, -3.0e38f, -3.0e38f, -3.0e38f);
                float4 m1 = m0;
                for (int e = 0; e < len; e++) {
                    int j = lst[(a * 2 + cc) * 96 + e];
                    const float4* hr = (const float4*)(hs + j * 128 + hq * 8);
                    m0 = max4(m0, hr[0]);
                    m1 = max4(m1, hr[1]);
                }
                float mm[8] = {m0.x, m0.y, m0.z, m0.w, m1.x, m1.y, m1.z, m1.w};
                #pragma unroll
                for (int u = 0; u < 8; u++)
                    AsT[(cc * 128 + hq * 8 + u) * 20 + a] = (len > 0) ? mm[u] : 0.f;
            }
            __syncthreads();
            {   // soc GEMM: 16r x 128o x K256; tile 4x8; in-wave 8-way ksplit
                // t bits: [2:0]=og_lo, [5:3]=ks, [6]=og_hi, [8:7]=rowg
                int og = (t & 7) | (((t >> 6) & 1) << 3);   // 0..15 (8 cols each)
                int ks = (t >> 3) & 7;
                int rowg = t >> 7;                           // 0..3 (4 rows each)
                float acc[4][8];
                #pragma unroll
                for (int r = 0; r < 4; r++)
                    #pragma unroll
                    for (int o = 0; o < 8; o++) acc[r][o] = 0.f;
                const float4* W4 = (const float4*)Wt_pool;  // [2048][32]
                int kb = kc * 256 + ks * 32;
                #pragma unroll 4
                for (int kk = 0; kk < 32; kk++) {
                    int kl = ks * 32 + kk;
                    float4 a4 = *(const float4*)&AsT[kl * 20 + rowg * 4];  // rows rowg*4..+3 (bcast)
                    float4 w0 = W4[(kb + kk) * 32 + og * 2];
                    float4 w1 = W4[(kb + kk) * 32 + og * 2 + 1];
                    float ar[4] = {a4.x, a4.y, a4.z, a4.w};
                    float wo[8] = {w0.x, w0.y, w0.z, w0.w, w1.x, w1.y, w1.z, w1.w};
                    #pragma unroll
                    for (int r = 0; r < 4; r++)
                        #pragma unroll
                        for (int o = 0; o < 8; o++)
                            acc[r][o] = fmaf(ar[r], wo[o], acc[r][o]);
                }
                #pragma unroll
                for (int r = 0; r < 4; r++)
                    #pragma unroll
                    for (int o = 0; o < 8; o++) {
                        acc[r][o] += __shfl_xor(acc[r][o], 8);
                        acc[r][o] += __shfl_xor(acc[r][o], 16);
                        acc[r][o] += __shfl_xor(acc[r][o], 32);
                    }
                if ((t & 56) == 0) {   // ks == 0 lanes write directly
                    #pragma unroll
                    for (int r = 0; r < 4; r++) {
                        int row = R0 + rowg * 4 + r;
                        float* pp = part + kc * 65536 + row * 128 + og * 8;
                        *(float4*)pp       = make_float4(acc[r][0], acc[r][1], acc[r][2], acc[r][3]);
                        *(float4*)(pp + 4) = make_float4(acc[r][4], acc[r][5], acc[r][6], acc[r][7]);
                    }
                }
            }
        }
        grid_barrier(flags, gen, seq++);

        // ===== Phase CD: gates GEMM (h-aligned) + pointwise LSTM =====
        {
            float* AsT = (float*)smem_raw;                 // [320][20]
            float* red = (float*)(smem_raw + 25600);       // [16][64]
            {   // stage emb rows (k 0..63): thread = (r, e2)
                int r = t >> 5, e2 = (t & 31) * 2;
                float2 v = *(const float2*)&emb[(R0 + r) * 64 + e2];
                AsT[(e2 + 0) * 20 + r] = v.x;
                AsT[(e2 + 1) * 20 + r] = v.y;
            }
            {   // stage soc rows (k 64..191): reduce part over kc + bias + relu
                int r = t >> 5, p4 = (t & 31) * 4;
                float sv[4] = {0, 0, 0, 0};
                for (int kc2 = 0; kc2 < 8; kc2++) {
                    float4 v = *(const float4*)(part + kc2 * 65536 + (R0 + r) * 128 + p4);
                    sv[0] += v.x; sv[1] += v.y; sv[2] += v.z; sv[3] += v.w;
                }
                #pragma unroll
                for (int u = 0; u < 4; u++)
                    AsT[(64 + p4 + u) * 20 + r] = fmaxf(sv[u] + b_pool[p4 + u], 0.f);
            }
            {   // stage hs rows (k 192..319)
                int r = t >> 5, h4 = (t & 31) * 4;
                float4 v = *(const float4*)(hs + (R0 + r) * 128 + h4);
                AsT[(192 + h4 + 0) * 20 + r] = v.x;
                AsT[(192 + h4 + 1) * 20 + r] = v.y;
                AsT[(192 + h4 + 2) * 20 + r] = v.z;
                AsT[(192 + h4 + 3) * 20 + r] = v.w;
            }
            __syncthreads();
            {   // gates GEMM: 16r x 64o x K320; tile 4x4; in-wave 8-way ksplit
                int og = (t & 7) | (((t >> 6) & 1) << 3);   // 0..15 (4 cols each)
                int ks = (t >> 3) & 7;
                int rowg = t >> 7;
                int col4 = (og >> 2) * 32 + hc * 4 + (og & 3);   // float4 col in Wt_g
                float acc[4][4];
                #pragma unroll
                for (int r = 0; r < 4; r++)
                    #pragma unroll
                    for (int o = 0; o < 4; o++) acc[r][o] = 0.f;
                const float4* Wg4 = (const float4*)Wt_g;    // [320][128]
                #pragma unroll 4
                for (int kk = 0; kk < 40; kk++) {
                    int k = ks * 40 + kk;
                    float4 a4 = *(const float4*)&AsT[k * 20 + rowg * 4];
                    float4 w  = Wg4[k * 128 + col4];
                    float ar[4] = {a4.x, a4.y, a4.z, a4.w};
                    float wo[4] = {w.x, w.y, w.z, w.w};
                    #pragma unroll
                    for (int r = 0; r < 4; r++)
                        #pragma unroll
                        for (int o = 0; o < 4; o++)
                            acc[r][o] = fmaf(ar[r], wo[o], acc[r][o]);
                }
                #pragma unroll
                for (int r = 0; r < 4; r++)
                    #pragma unroll
                    for (int o = 0; o < 4; o++) {
                        acc[r][o] += __shfl_xor(acc[r][o], 8);
                        acc[r][o] += __shfl_xor(acc[r][o], 16);
                        acc[r][o] += __shfl_xor(acc[r][o], 32);
                    }
                if ((t & 56) == 0) {
                    #pragma unroll
                    for (int r = 0; r < 4; r++)
                        *(float4*)&red[(rowg * 4 + r) * 64 + og * 4] =
                            make_float4(acc[r][0], acc[r][1], acc[r][2], acc[r][3]);
                }
            }
            __syncthreads();
            if (t < 256) {   // pointwise LSTM: thread (rl, hh)
                int rl = t >> 4, hh = t & 15;
                float g4[4];
                #pragma unroll
                for (int q = 0; q < 4; q++) {
                    int colq = q * 128 + hc * 16 + hh;
                    g4[q] = red[rl * 64 + q * 16 + hh] + bihp[colq] + bhhp[colq];
                }
                float si = sigm(g4[0]);
                float sf = sigm(g4[1]);
                float so = sigm(g4[3]);
                float c2 = sf * cs_reg + si * tanhf(g4[2]);
                float h2 = so * tanhf(c2);
                cs_reg = c2;
                int i = R0 + rl, h = hc * 16 + hh;
                hs[i * 128 + h] = h2;
                if (s >= 7) {
                    float v0 = W_out[h] * h2;
                    float v1 = W_out[128 + h] * h2;
                    v0 += __shfl_down(v0, 8); v0 += __shfl_down(v0, 4);
                    v0 += __shfl_down(v0, 2); v0 += __shfl_down(v0, 1);
                    v1 += __shfl_down(v1, 8); v1 += __shfl_down(v1, 4);
                    v1 += __shfl_down(v1, 2); v1 += __shfl_down(v1, 1);
                    if (hh == 0) {
                        atomicAdd(&out[(s - 7) * 1024 + 2 * i],     v0);
                        atomicAdd(&out[(s - 7) * 1024 + 2 * i + 1], v1);
                    }
                }
            }
        }
        grid_barrier(flags, gen, seq++);
    }
}

extern "C" void kernel_launch(void* const* d_in, const int* in_sizes, int n_in,
                              void* d_out, int out_size, void* d_ws, size_t ws_size,
                              hipStream_t stream) {
    const float* observed = (const float*)d_in[0];
    const float* W_pos    = (const float*)d_in[1];
    const float* b_pos    = (const float*)d_in[2];
    const float* W_pool   = (const float*)d_in[3];
    const float* b_pool   = (const float*)d_in[4];
    const float* Wih_e    = (const float*)d_in[5];
    const float* bih_e    = (const float*)d_in[6];
    const float* Whh_e    = (const float*)d_in[7];
    const float* bhh_e    = (const float*)d_in[8];
    const float* Wih_d    = (const float*)d_in[9];
    const float* bih_d    = (const float*)d_in[10];
    const float* Whh_d    = (const float*)d_in[11];
    const float* bhh_d    = (const float*)d_in[12];
    const float* W_out    = (const float*)d_in[13];
    const float* b_out    = (const float*)d_in[14];
    float* outp = (float*)d_out;
    float* wsp  = (float*)d_ws;
    int npred = out_size / 1024;

    // zero flags (16 KB) + gen
    hipMemsetAsync(d_ws, 0, 20480, stream);

    social_lstm<<<NBLK, NTHR, LDS_BYTES, stream>>>(
        observed, W_pos, b_pos, W_pool, b_pool,
        Wih_e, bih_e, Whh_e, bhh_e,
        Wih_d, bih_d, Whh_d, bhh_d,
        W_out, b_out, outp, wsp, npred);
}

// Round 9
// 819.482 us; speedup vs baseline: 2.9302x; 1.1124x over previous
//
#include <hip/hip_runtime.h>
#include <math.h>

#define NBLK 256
#define NTHR 512

// ---- ws layout ----
// uints [0..8191]: block b arrival flag at b*16; gen at [4096]; cnt_rt[rt] at [4352+rt*16]
// floats from 8256:
#define OFF_OBS     8256        // 8192
#define OFF_HS      16448       // 65536
#define OFF_PART    81984       // 524288  (8 kc x 512 x 128) -- L2-BYPASS access only
#define OFF_WTPOOL  606272      // 262144  (Wt_pool [2048][128])
#define OFF_WTG_E   868416      // 163840
#define OFF_WTG_D   1032256     // 163840
// end 1196096 floats = 4.8 MB

#define LDS_BYTES 30848

// ext-vector types: required for inline-asm "v" constraints (HIP float4 is a
// struct -> "indirect register inputs" compile error)
typedef float vf4 __attribute__((ext_vector_type(4)));
typedef float vf2 __attribute__((ext_vector_type(2)));

// ---------- L2-bypass (device-coherent at LLC) vector access ----------
__device__ __forceinline__ void st_bypass_f4(float* p, vf4 v) {
    asm volatile("global_store_dwordx4 %0, %1, off sc0 sc1" :: "v"(p), "v"(v) : "memory");
}
__device__ __forceinline__ void st_bypass_f2(float* p, vf2 v) {
    asm volatile("global_store_dwordx2 %0, %1, off sc0 sc1" :: "v"(p), "v"(v) : "memory");
}
__device__ __forceinline__ void ld_bypass_f4x8(const float* b, int stride, vf4* v) {
    asm volatile(
        "global_load_dwordx4 %0, %8, off sc0 sc1\n\t"
        "global_load_dwordx4 %1, %9, off sc0 sc1\n\t"
        "global_load_dwordx4 %2, %10, off sc0 sc1\n\t"
        "global_load_dwordx4 %3, %11, off sc0 sc1\n\t"
        "global_load_dwordx4 %4, %12, off sc0 sc1\n\t"
        "global_load_dwordx4 %5, %13, off sc0 sc1\n\t"
        "global_load_dwordx4 %6, %14, off sc0 sc1\n\t"
        "global_load_dwordx4 %7, %15, off sc0 sc1\n\t"
        "s_waitcnt vmcnt(0)"
        : "=&v"(v[0]), "=&v"(v[1]), "=&v"(v[2]), "=&v"(v[3]),
          "=&v"(v[4]), "=&v"(v[5]), "=&v"(v[6]), "=&v"(v[7])
        : "v"(b), "v"(b + stride), "v"(b + 2 * stride), "v"(b + 3 * stride),
          "v"(b + 4 * stride), "v"(b + 5 * stride), "v"(b + 6 * stride), "v"(b + 7 * stride)
        : "memory");
}

// Global barrier with release(wbl2) / acquire(inv) fences; RELAXED polls.
__device__ __forceinline__ void grid_barrier(unsigned* flags, unsigned* gen, unsigned seq) {
    __syncthreads();
    if (threadIdx.x == 0)
        __builtin_amdgcn_fence(__ATOMIC_RELEASE, "agent");   // wbl2
    if (blockIdx.x == 0) {
        if (threadIdx.x < 64) {
            #pragma unroll
            for (int q = 0; q < 4; q++) {
                int bb = threadIdx.x * 4 + q;
                if (bb != 0) {
                    while (__hip_atomic_load(&flags[bb * 16], __ATOMIC_RELAXED,
                                             __HIP_MEMORY_SCOPE_AGENT) != seq)
                        __builtin_amdgcn_s_sleep(1);
                }
            }
        }
        __syncthreads();
        if (threadIdx.x == 0) {
            __hip_atomic_store(gen, seq, __ATOMIC_RELAXED, __HIP_MEMORY_SCOPE_AGENT);
            __builtin_amdgcn_fence(__ATOMIC_ACQUIRE, "agent");  // inv
        }
    } else {
        if (threadIdx.x == 0) {
            __hip_atomic_store(&flags[blockIdx.x * 16], seq, __ATOMIC_RELAXED,
                               __HIP_MEMORY_SCOPE_AGENT);
            while (__hip_atomic_load(gen, __ATOMIC_RELAXED,
                                     __HIP_MEMORY_SCOPE_AGENT) != seq)
                __builtin_amdgcn_s_sleep(2);
            __builtin_amdgcn_fence(__ATOMIC_ACQUIRE, "agent");  // inv
        }
    }
    __syncthreads();
}

__device__ __forceinline__ float sigm(float x) { return 1.f / (1.f + expf(-x)); }
__device__ __forceinline__ float4 max4(float4 a, float4 b) {
    return make_float4(fmaxf(a.x, b.x), fmaxf(a.y, b.y), fmaxf(a.z, b.z), fmaxf(a.w, b.w));
}

__global__ void __launch_bounds__(NTHR, 1) social_lstm(
    const float* __restrict__ observed,
    const float* __restrict__ W_pos, const float* __restrict__ b_pos,
    const float* __restrict__ W_pool, const float* __restrict__ b_pool,
    const float* __restrict__ Wih_e, const float* __restrict__ bih_e,
    const float* __restrict__ Whh_e, const float* __restrict__ bhh_e,
    const float* __restrict__ Wih_d, const float* __restrict__ bih_d,
    const float* __restrict__ Whh_d, const float* __restrict__ bhh_d,
    const float* __restrict__ W_out, const float* __restrict__ b_out,
    float* __restrict__ out, float* __restrict__ ws, int npred)
{
    extern __shared__ char smem_raw[];
    const int t = threadIdx.x, b = blockIdx.x;
    const int gid = b * NTHR + t;

    unsigned* flags  = (unsigned*)ws;
    unsigned* gen    = flags + 4096;
    unsigned* cnt_rt = flags + 4352;            // [rt*16], monotonic
    float* obs     = ws + OFF_OBS;
    float* hs      = ws + OFF_HS;
    float* part    = ws + OFF_PART;
    float* Wt_pool = ws + OFF_WTPOOL;
    float* Wt_ge   = ws + OFF_WTG_E;
    float* Wt_gd   = ws + OFF_WTG_D;
    unsigned seq = 1;

    // ================= init =================
    if (gid < 65536) hs[gid] = 0.f;
    if (gid < 512) {
        float vx[8], vy[8];
        int fin = 0;
        for (int tt = 0; tt < 8; tt++) {
            float x = observed[tt * 1024 + gid * 2];
            float y = observed[tt * 1024 + gid * 2 + 1];
            vx[tt] = x; vy[tt] = y;
            if (isfinite(x) && isfinite(y)) fin |= (1 << tt);
        }
        int firstv = -1;
        for (int tt = 7; tt >= 0; tt--) if (fin & (1 << tt)) firstv = tt;
        int last = -1;
        for (int tt = 0; tt < 8; tt++) {
            if (fin & (1 << tt)) last = tt;
            int take = (last >= 0) ? last : firstv;
            float ox = 0.f, oy = 0.f;
            if (take >= 0) { ox = vx[take]; oy = vy[take]; }
            obs[tt * 1024 + gid * 2]     = ox;
            obs[tt * 1024 + gid * 2 + 1] = oy;
        }
    }
    if (gid < 65536) {   // Wt_pool[k][p] = W_pool[p][k]
        int p = gid >> 9, k4 = gid & 511;
        float4 v = *(const float4*)(W_pool + p * 2048 + k4 * 4);
        float* dst = Wt_pool + (k4 * 4) * 128 + p;
        dst[0] = v.x; dst[128] = v.y; dst[256] = v.z; dst[384] = v.w;
    }
    for (int idx = gid; idx < 163840; idx += NBLK * NTHR) {
        int k = idx >> 9, o = idx & 511;
        float ve, vd;
        if (k < 192) { ve = Wih_e[o * 192 + k];       vd = Wih_d[o * 192 + k]; }
        else         { ve = Whh_e[o * 128 + k - 192]; vd = Whh_d[o * 128 + k - 192]; }
        Wt_ge[idx] = ve; Wt_gd[idx] = vd;
    }
    grid_barrier(flags, gen, seq++);

    const int rt = b >> 3, kc = b & 7, hc = kc;
    const int R0 = rt * 16;
    float cs_reg = 0.f;       // t<256: rl=t>>4, hh=t&15
    const int nstep = 7 + npred;

    for (int s = 0; s < nstep; s++) {
        const float* posp  = (s < 7) ? (obs + (s + 1) * 1024)
                                     : ((s == 7) ? (obs + 7 * 1024) : (out + (s - 8) * 1024));
        const float* prevp = (s < 7) ? (obs + s * 1024)
                                     : ((s <= 8) ? (obs + 7 * 1024) : (out + (s - 9) * 1024));
        const float* Wt_g = (s < 7) ? Wt_ge : Wt_gd;
        const float* bihp = (s < 7) ? bih_e : bih_d;
        const float* bhhp = (s < 7) ? bhh_e : bhh_d;

        // ===== Phase AB: prefetch + pooling (2 cells) + soc GEMM K-chunk =====
        {
            float* pos2 = (float*)smem_raw;                           // 1024 f
            int* cnt    = (int*)(smem_raw + 4096);                    // 32 i
            unsigned short* lst = (unsigned short*)(smem_raw + 4224); // 32*96 us
            float* AsT  = (float*)(smem_raw + 10368);                 // 256*20 f

            // ---- prefetch (post-inv L2 warm, one float4 per 64B line, big MLP) ----
            float4 pf = make_float4(0.f, 0.f, 0.f, 0.f);
            {
                const float4* H4p = (const float4*)hs;
                #pragma unroll
                for (int q = 0; q < 8; q++) {               // hs: 4096 lines
                    int idx = t + q * 512;
                    float4 v = H4p[idx * 4];
                    pf.x += v.x; pf.y += v.y; pf.z += v.z; pf.w += v.w;
                }
                const float4* Wp4 = (const float4*)Wt_pool;
                #pragma unroll
                for (int q = 0; q < 4; q++) {               // Wt_pool slice: 2048 lines
                    int idx = t + q * 512;
                    float4 v = Wp4[kc * 8192 + idx * 4];
                    pf.x += v.x; pf.y += v.y; pf.z += v.z; pf.w += v.w;
                }
                const float4* Wg4p = (const float4*)Wt_g;
                for (int idx = t; idx < 1280; idx += 512) { // Wt_g slice: 1280 lines
                    int k = idx >> 2, g = idx & 3;
                    float4 v = Wg4p[k * 128 + g * 32 + hc * 4];
                    pf.x += v.x; pf.y += v.y; pf.z += v.z; pf.w += v.w;
                }
            }

            if (t < 256) ((float4*)pos2)[t] = ((const float4*)posp)[t];
            if (t < 32) cnt[t] = 0;
            __syncthreads();

            if (kc == 1 && s >= 7 && t < 16) {  // init out row = pos + b_out (bypass: LLC)
                int i = R0 + t;
                vf2 v;
                v.x = pos2[2 * i] + b_out[0];
                v.y = pos2[2 * i + 1] + b_out[1];
                st_bypass_f2(out + (s - 7) * 1024 + 2 * i, v);
            }
            {   // pair eval: agent a = t>>5, 32 threads/agent
                int a = t >> 5, i = R0 + a;
                float pix = pos2[2 * i], piy = pos2[2 * i + 1];
                int c0 = kc * 2;
                for (int jj = 0; jj < 16; jj++) {
                    int j = (t & 31) + jj * 32;
                    float dx = pos2[2 * j]     - pix;
                    float dy = pos2[2 * j + 1] - piy;
                    if (j != i && fabsf(dx) <= 1.0f && fabsf(dy) <= 1.0f) {
                        int gx = (int)floorf((dx + 1.0f) * 2.0f); gx = gx < 0 ? 0 : (gx > 3 ? 3 : gx);
                        int gy = (int)floorf((dy + 1.0f) * 2.0f); gy = gy < 0 ? 0 : (gy > 3 ? 3 : gy);
                        int cc = gx * 4 + gy - c0;
                        if (cc == 0 || cc == 1) {
                            int slot = atomicAdd(&cnt[a * 2 + cc], 1);
                            if (slot < 96) lst[(a * 2 + cc) * 96 + slot] = (unsigned short)j;
                        }
                    }
                }
            }
            __syncthreads();
            {   // cell max -> AsT[k][agent]: thread = (a, cc, hq); hs L2-warm
                int a = t >> 5, cc = (t >> 4) & 1, hq = t & 15;
                int len = cnt[a * 2 + cc]; if (len > 96) len = 96;
                float4 m0 = make_float4(-3.0e38f, -3.0e38f, -3.0e38f, -3.0e38f);
                float4 m1 = m0;
                for (int e = 0; e < len; e++) {
                    int j = lst[(a * 2 + cc) * 96 + e];
                    const float4* hr = (const float4*)(hs + j * 128 + hq * 8);
                    m0 = max4(m0, hr[0]);
                    m1 = max4(m1, hr[1]);
                }
                float mm[8] = {m0.x, m0.y, m0.z, m0.w, m1.x, m1.y, m1.z, m1.w};
                #pragma unroll
                for (int u = 0; u < 8; u++)
                    AsT[(cc * 128 + hq * 8 + u) * 20 + a] = (len > 0) ? mm[u] : 0.f;
            }
            __syncthreads();
            {   // soc GEMM: 16r x 128o x K256; tile 4x8; in-wave 8-way ksplit
                int og = (t & 7) | (((t >> 6) & 1) << 3);
                int ks = (t >> 3) & 7;
                int rowg = t >> 7;
                float acc[4][8];
                #pragma unroll
                for (int r = 0; r < 4; r++)
                    #pragma unroll
                    for (int o = 0; o < 8; o++) acc[r][o] = 0.f;
                const float4* W4 = (const float4*)Wt_pool;
                int kb = kc * 256 + ks * 32;
                #pragma unroll 4
                for (int kk = 0; kk < 32; kk++) {
                    int kl = ks * 32 + kk;
                    float4 a4 = *(const float4*)&AsT[kl * 20 + rowg * 4];
                    float4 w0 = W4[(kb + kk) * 32 + og * 2];
                    float4 w1 = W4[(kb + kk) * 32 + og * 2 + 1];
                    float ar[4] = {a4.x, a4.y, a4.z, a4.w};
                    float wo[8] = {w0.x, w0.y, w0.z, w0.w, w1.x, w1.y, w1.z, w1.w};
                    #pragma unroll
                    for (int r = 0; r < 4; r++)
                        #pragma unroll
                        for (int o = 0; o < 8; o++)
                            acc[r][o] = fmaf(ar[r], wo[o], acc[r][o]);
                }
                #pragma unroll
                for (int r = 0; r < 4; r++)
                    #pragma unroll
                    for (int o = 0; o < 8; o++) {
                        acc[r][o] += __shfl_xor(acc[r][o], 8);
                        acc[r][o] += __shfl_xor(acc[r][o], 16);
                        acc[r][o] += __shfl_xor(acc[r][o], 32);
                    }
                if ((t & 56) == 0) {   // ks==0 lanes: bypass stores (LLC-coherent)
                    #pragma unroll
                    for (int r = 0; r < 4; r++) {
                        int row = R0 + rowg * 4 + r;
                        float* pp = part + kc * 65536 + row * 128 + og * 8;
                        vf4 lo, hi;
                        lo.x = acc[r][0]; lo.y = acc[r][1]; lo.z = acc[r][2]; lo.w = acc[r][3];
                        hi.x = acc[r][4]; hi.y = acc[r][5]; hi.z = acc[r][6]; hi.w = acc[r][7];
                        st_bypass_f4(pp,     lo);
                        st_bypass_f4(pp + 4, hi);
                    }
                }
            }
            // consume prefetch sums (never true; blocks DCE)
            if (pf.x + pf.y + pf.z + pf.w == 1.23456e30f)
                ((volatile float*)smem_raw)[0] = 1.f;
        }

        // ---- local 8-producer sync for this row-group (NO fences, NO global barrier) ----
        __syncthreads();                 // drains this block's bypass stores (vmcnt)
        if (t == 0) {
            __hip_atomic_fetch_add(&cnt_rt[rt * 16], 1u, __ATOMIC_RELAXED, __HIP_MEMORY_SCOPE_AGENT);
            unsigned tgt = 8u * (unsigned)(s + 1);
            while (__hip_atomic_load(&cnt_rt[rt * 16], __ATOMIC_RELAXED,
                                     __HIP_MEMORY_SCOPE_AGENT) != tgt)
                __builtin_amdgcn_s_sleep(1);
        }
        __syncthreads();

        // ===== Phase CD: gates GEMM (h-aligned) + pointwise LSTM =====
        {
            float* AsT = (float*)smem_raw;                 // [320][20]
            float* red = (float*)(smem_raw + 25600);       // [16][64]
            {   // stage emb rows (k 0..63): computed locally (no cross-block emb)
                int r = t >> 5, e2 = (t & 31) * 2;
                int i2 = 2 * (R0 + r);
                float vx = posp[i2]     - prevp[i2];
                float vy = posp[i2 + 1] - prevp[i2 + 1];
                float e0 = fmaxf(W_pos[e2 * 2]     * vx + W_pos[e2 * 2 + 1] * vy + b_pos[e2],     0.f);
                float e1 = fmaxf(W_pos[e2 * 2 + 2] * vx + W_pos[e2 * 2 + 3] * vy + b_pos[e2 + 1], 0.f);
                AsT[(e2 + 0) * 20 + r] = e0;
                AsT[(e2 + 1) * 20 + r] = e1;
            }
            {   // stage soc rows (k 64..191): bypass-batched part reduce + bias + relu
                int r = t >> 5, p4 = (t & 31) * 4;
                vf4 pv[8];
                ld_bypass_f4x8(part + (R0 + r) * 128 + p4, 65536, pv);
                float sv[4] = {0.f, 0.f, 0.f, 0.f};
                #pragma unroll
                for (int kc2 = 0; kc2 < 8; kc2++) {
                    sv[0] += pv[kc2].x; sv[1] += pv[kc2].y;
                    sv[2] += pv[kc2].z; sv[3] += pv[kc2].w;
                }
                #pragma unroll
                for (int u = 0; u < 4; u++)
                    AsT[(64 + p4 + u) * 20 + r] = fmaxf(sv[u] + b_pool[p4 + u], 0.f);
            }
            {   // stage hs rows (k 192..319)
                int r = t >> 5, h4 = (t & 31) * 4;
                float4 v = *(const float4*)(hs + (R0 + r) * 128 + h4);
                AsT[(192 + h4 + 0) * 20 + r] = v.x;
                AsT[(192 + h4 + 1) * 20 + r] = v.y;
                AsT[(192 + h4 + 2) * 20 + r] = v.z;
                AsT[(192 + h4 + 3) * 20 + r] = v.w;
            }
            __syncthreads();
            {   // gates GEMM: 16r x 64o x K320; tile 4x4; in-wave 8-way ksplit
                int og = (t & 7) | (((t >> 6) & 1) << 3);
                int ks = (t >> 3) & 7;
                int rowg = t >> 7;
                int col4 = (og >> 2) * 32 + hc * 4 + (og & 3);
                float acc[4][4];
                #pragma unroll
                for (int r = 0; r < 4; r++)
                    #pragma unroll
                    for (int o = 0; o < 4; o++) acc[r][o] = 0.f;
                const float4* Wg4 = (const float4*)Wt_g;    // L2-warm from AB prefetch
                #pragma unroll 4
                for (int kk = 0; kk < 40; kk++) {
                    int k = ks * 40 + kk;
                    float4 a4 = *(const float4*)&AsT[k * 20 + rowg * 4];
                    float4 w  = Wg4[k * 128 + col4];
                    float ar[4] = {a4.x, a4.y, a4.z, a4.w};
                    float wo[4] = {w.x, w.y, w.z, w.w};
                    #pragma unroll
                    for (int r = 0; r < 4; r++)
                        #pragma unroll
                        for (int o = 0; o < 4; o++)
                            acc[r][o] = fmaf(ar[r], wo[o], acc[r][o]);
                }
                #pragma unroll
                for (int r = 0; r < 4; r++)
                    #pragma unroll
                    for (int o = 0; o < 4; o++) {
                        acc[r][o] += __shfl_xor(acc[r][o], 8);
                        acc[r][o] += __shfl_xor(acc[r][o], 16);
                        acc[r][o] += __shfl_xor(acc[r][o], 32);
                    }
                if ((t & 56) == 0) {
                    #pragma unroll
                    for (int r = 0; r < 4; r++)
                        *(float4*)&red[(rowg * 4 + r) * 64 + og * 4] =
                            make_float4(acc[r][0], acc[r][1], acc[r][2], acc[r][3]);
                }
            }
            __syncthreads();
            if (t < 256) {   // pointwise LSTM
                int rl = t >> 4, hh = t & 15;
                float g4[4];
                #pragma unroll
                for (int q = 0; q < 4; q++) {
                    int colq = q * 128 + hc * 16 + hh;
                    g4[q] = red[rl * 64 + q * 16 + hh] + bihp[colq] + bhhp[colq];
                }
                float si = sigm(g4[0]);
                float sf = sigm(g4[1]);
                float so = sigm(g4[3]);
                float c2 = sf * cs_reg + si * tanhf(g4[2]);
                float h2 = so * tanhf(c2);
                cs_reg = c2;
                int i = R0 + rl, h = hc * 16 + hh;
                hs[i * 128 + h] = h2;                 // cached; flushed by end barrier wbl2
                if (s >= 7) {
                    float v0 = W_out[h] * h2;
                    float v1 = W_out[128 + h] * h2;
                    v0 += __shfl_down(v0, 8); v0 += __shfl_down(v0, 4);
                    v0 += __shfl_down(v0, 2); v0 += __shfl_down(v0, 1);
                    v1 += __shfl_down(v1, 8); v1 += __shfl_down(v1, 4);
                    v1 += __shfl_down(v1, 2); v1 += __shfl_down(v1, 1);
                    if (hh == 0) {
                        atomicAdd(&out[(s - 7) * 1024 + 2 * i],     v0);
                        atomicAdd(&out[(s - 7) * 1024 + 2 * i + 1], v1);
                    }
                }
            }
        }
        grid_barrier(flags, gen, seq++);   // end-of-step: wbl2 (hs) + inv (hs stale copies)
    }
}

extern "C" void kernel_launch(void* const* d_in, const int* in_sizes, int n_in,
                              void* d_out, int out_size, void* d_ws, size_t ws_size,
                              hipStream_t stream) {
    const float* observed = (const float*)d_in[0];
    const float* W_pos    = (const float*)d_in[1];
    const float* b_pos    = (const float*)d_in[2];
    const float* W_pool   = (const float*)d_in[3];
    const float* b_pool   = (const float*)d_in[4];
    const float* Wih_e    = (const float*)d_in[5];
    const float* bih_e    = (const float*)d_in[6];
    const float* Whh_e    = (const float*)d_in[7];
    const float* bhh_e    = (const float*)d_in[8];
    const float* Wih_d    = (const float*)d_in[9];
    const float* bih_d    = (const float*)d_in[10];
    const float* Whh_d    = (const float*)d_in[11];
    const float* bhh_d    = (const float*)d_in[12];
    const float* W_out    = (const float*)d_in[13];
    const float* b_out    = (const float*)d_in[14];
    float* outp = (float*)d_out;
    float* wsp  = (float*)d_ws;
    int npred = out_size / 1024;

    // zero flags + gen + cnt_rt (first 8192 uints)
    hipMemsetAsync(d_ws, 0, 33024, stream);

    social_lstm<<<NBLK, NTHR, LDS_BYTES, stream>>>(
        observed, W_pos, b_pos, W_pool, b_pool,
        Wih_e, bih_e, Whh_e, bhh_e,
        Wih_d, bih_d, Whh_d, bhh_d,
        W_out, b_out, outp, wsp, npred);
}